// Round 10
// baseline (987.896 us; speedup 1.0000x reference)
//
#include <hip/hip_runtime.h>
#include <hip/hip_bf16.h>

using bf16 = __hip_bfloat16;
typedef __attribute__((ext_vector_type(8))) short short8;
typedef __attribute__((ext_vector_type(4))) float float4v;

constexpr int NTOK = 131072;  // 2*256*256

// ---------------- workspace layout (bytes) ----------------
constexpr size_t OFF_T1   = 50331648;    // f32  [131072][24]     12,582,912
constexpr size_t OFF_T2   = 62914560;    // f32  [131072][24]     12,582,912
constexpr size_t OFF_S0   = 75497472;    // f32  [2][192]
constexpr size_t OFF_WQKV = 75500544;    // bf16 [576][192]       221,184
constexpr size_t OFF_WPRJ = 75721728;    // bf16 [192][192]        73,728
constexpr size_t OFF_WFC1 = 75795456;    // bf16 [768][192]       294,912
constexpr size_t OFF_WFC2 = 76090368;    // bf16 [192][768]       294,912
constexpr size_t OFF_C1WB = 76385280;    // bf16 [32][192]         12,288 (rows 24..31 zero)
constexpr size_t WS_NEEDED = 76397568;

__device__ __forceinline__ int region256(int t) { return t < 248 ? 0 : (t < 252 ? 1 : 2); }

__device__ __forceinline__ short8 lds8(const bf16* p) {
  return *reinterpret_cast<const short8*>(p);
}
__device__ __forceinline__ short8 glb8(const bf16* p) {
  return *reinterpret_cast<const short8*>(p);
}

// ---------------- fp32 -> bf16 weight convert + zero-init (one dispatch) ----------------
__global__ __launch_bounds__(256) void k_f2b_all(const float* __restrict__ qkvw, const float* __restrict__ projw,
                                                 const float* __restrict__ w1, const float* __restrict__ w2,
                                                 const float* __restrict__ c1w,
                                                 bf16* __restrict__ wqkv, bf16* __restrict__ wprj,
                                                 bf16* __restrict__ wfc1, bf16* __restrict__ wfc2,
                                                 bf16* __restrict__ c1wb, float* __restrict__ s0) {
  int i = blockIdx.x * 256 + threadIdx.x;
  if (i < 110592) { wqkv[i] = __float2bfloat16(qkvw[i]); return; }
  i -= 110592;
  if (i < 36864) { wprj[i] = __float2bfloat16(projw[i]); return; }
  i -= 36864;
  if (i < 147456) { wfc1[i] = __float2bfloat16(w1[i]); return; }
  i -= 147456;
  if (i < 147456) { wfc2[i] = __float2bfloat16(w2[i]); return; }
  i -= 147456;
  if (i < 4608) { c1wb[i] = __float2bfloat16(c1w[i]); return; }
  i -= 4608;
  if (i < 1536) { c1wb[4608 + i] = __float2bfloat16(0.f); return; }  // pad rows 24..31
  i -= 1536;
  if (i < 384) s0[i] = 0.f;
}

// ---------------- chunked fused attention (+ LCE conv1) ----------------
// R9 lesson: 6-deep batches fit in ~115 regs (84 arch + ~30 acc) -> under the
// (256,4) cap of 128. R8's spill was the 12-deep (48-reg) batches, not
// batching itself. This round: wf[6] batches + (256,4) = prefetch AND
// 4 blocks/CU together. Spill check: FETCH must stay ~102 MB.
__device__ __forceinline__ int stg_b(int r, int c) { return (r * 384 + c * 2) ^ ((r & 7) << 4); }
__device__ __forceinline__ int kl1_b(int r, int c) { return 24576 + ((r * 64 + c * 2) ^ ((r & 7) << 4)); }
__device__ __forceinline__ int vt1_b(int r, int c) { return 28672 + ((r * 128 + c * 2) ^ ((r & 7) << 4)); }
__device__ __forceinline__ int ps3_b(int r, int c) { return 32768 + ((r * 128 + c * 2) ^ ((r & 7) << 4)); }

__device__ __forceinline__ short8 lds8o(const char* sm, int byteoff) {
  return *reinterpret_cast<const short8*>(sm + byteoff);
}
__device__ __forceinline__ void st16(char* sm, int byteoff, bf16 v) {
  *reinterpret_cast<bf16*>(sm + byteoff) = v;
}

__global__ __launch_bounds__(256, 4) void k_attn2(const float* __restrict__ x, const float* __restrict__ g,
                                                  const float* __restrict__ bb, const bf16* __restrict__ wq,
                                                  const float* __restrict__ qkvb, const float* __restrict__ rpb,
                                                  const bf16* __restrict__ wp, const float* __restrict__ projb,
                                                  const bf16* __restrict__ c1wb, const float* __restrict__ c1b,
                                                  float* __restrict__ t1, float* __restrict__ x1out) {
  __shared__ char sm[40960];

  int win = blockIdx.x;
  int b = win >> 10;
  int wrem = win & 1023;
  int wh = wrem >> 5, ww = wrem & 31;
  int tid = threadIdx.x;
  int wave = tid >> 6, lane = tid & 63;
  int colB = lane & 15, grp = lane >> 4;
  const float scale = 0.17677669529663687f;  // 1/sqrt(32)

  // ---- Phase 1: LN over this wave's 16 tokens (gather with roll -4) -> staging (wave-private rows)
  for (int t = 0; t < 16; ++t) {
    int tok = wave * 16 + t;
    int i = tok >> 3, j = tok & 7;
    int hp = (wh * 8 + i + 4) & 255;
    int wpp = (ww * 8 + j + 4) & 255;
    const float* xr = x + (((size_t)b << 16) + (hp << 8) + wpp) * 192;
    float v0 = xr[lane], v1 = xr[lane + 64], v2 = xr[lane + 128];
    float s = v0 + v1 + v2;
    for (int o = 32; o > 0; o >>= 1) s += __shfl_down(s, o);
    s = __shfl(s, 0);
    float m = s * (1.f / 192.f);
    float d0 = v0 - m, d1 = v1 - m, d2 = v2 - m;
    float q = d0 * d0 + d1 * d1 + d2 * d2;
    for (int o = 32; o > 0; o >>= 1) q += __shfl_down(q, o);
    q = __shfl(q, 0);
    float inv = rsqrtf(q * (1.f / 192.f) + 1e-5f);
    st16(sm, stg_b(tok, lane),       __float2bfloat16(d0 * inv * g[lane]       + bb[lane]));
    st16(sm, stg_b(tok, lane + 64),  __float2bfloat16(d1 * inv * g[lane + 64]  + bb[lane + 64]));
    st16(sm, stg_b(tok, lane + 128), __float2bfloat16(d2 * inv * g[lane + 128] + bb[lane + 128]));
  }

  short8 axw[6];
#pragma unroll
  for (int kk = 0; kk < 6; ++kk) axw[kk] = lds8o(sm, stg_b(wave * 16 + colB, kk * 32 + 8 * grp));

  int l1r[4], i1r[4], j1r[4];
#pragma unroll
  for (int r = 0; r < 4; ++r) {
    int n = wave * 16 + 4 * grp + r;
    i1r[r] = n >> 3; j1r[r] = n & 7;
    l1r[r] = region256(wh * 8 + i1r[r]) * 3 + region256(ww * 8 + j1r[r]);
  }

  for (int gch = 0; gch < 6; ++gch) {  // chunk = head gch = qkv cols 32g..32g+31
    float qreg[8];
    {  // Q: two 6-frag prefetch batches (24 VGPR transient, reused)
      float4v qa[2] = {{0,0,0,0},{0,0,0,0}};
      short8 wf[6];
#pragma unroll
      for (int h2 = 0; h2 < 2; ++h2) {
#pragma unroll
        for (int kk = 0; kk < 3; ++kk)
#pragma unroll
          for (int jt = 0; jt < 2; ++jt)
            wf[kk * 2 + jt] = glb8(wq + (size_t)(gch * 32 + jt * 16 + colB) * 192 + (h2 * 3 + kk) * 32 + 8 * grp);
#pragma unroll
        for (int kk = 0; kk < 3; ++kk)
#pragma unroll
          for (int jt = 0; jt < 2; ++jt)
            qa[jt] = __builtin_amdgcn_mfma_f32_16x16x32_bf16(axw[h2 * 3 + kk], wf[kk * 2 + jt], qa[jt], 0, 0, 0);
      }
#pragma unroll
      for (int jt = 0; jt < 2; ++jt) {
        float bias = qkvb[gch * 32 + jt * 16 + colB];
#pragma unroll
        for (int r = 0; r < 4; ++r) qreg[jt * 4 + r] = (qa[jt][r] + bias) * scale;
      }
    }
    {  // K -> KL1: two 6-frag batches
      float4v ka[2] = {{0,0,0,0},{0,0,0,0}};
      short8 wf[6];
#pragma unroll
      for (int h2 = 0; h2 < 2; ++h2) {
#pragma unroll
        for (int kk = 0; kk < 3; ++kk)
#pragma unroll
          for (int jt = 0; jt < 2; ++jt)
            wf[kk * 2 + jt] = glb8(wq + (size_t)(192 + gch * 32 + jt * 16 + colB) * 192 + (h2 * 3 + kk) * 32 + 8 * grp);
#pragma unroll
        for (int kk = 0; kk < 3; ++kk)
#pragma unroll
          for (int jt = 0; jt < 2; ++jt)
            ka[jt] = __builtin_amdgcn_mfma_f32_16x16x32_bf16(axw[h2 * 3 + kk], wf[kk * 2 + jt], ka[jt], 0, 0, 0);
      }
#pragma unroll
      for (int jt = 0; jt < 2; ++jt) {
        float bias = qkvb[192 + gch * 32 + jt * 16 + colB];
#pragma unroll
        for (int r = 0; r < 4; ++r)
          st16(sm, kl1_b(wave * 16 + 4 * grp + r, jt * 16 + colB), __float2bfloat16(ka[jt][r] + bias));
      }
    }
    {  // V -> VT1 (transposed): two 6-frag batches
      float4v va[2] = {{0,0,0,0},{0,0,0,0}};
      short8 wf[6];
#pragma unroll
      for (int h2 = 0; h2 < 2; ++h2) {
#pragma unroll
        for (int kk = 0; kk < 3; ++kk)
#pragma unroll
          for (int jt = 0; jt < 2; ++jt)
            wf[kk * 2 + jt] = glb8(wq + (size_t)(384 + gch * 32 + jt * 16 + colB) * 192 + (h2 * 3 + kk) * 32 + 8 * grp);
#pragma unroll
        for (int kk = 0; kk < 3; ++kk)
#pragma unroll
          for (int jt = 0; jt < 2; ++jt)
            va[jt] = __builtin_amdgcn_mfma_f32_16x16x32_bf16(axw[h2 * 3 + kk], wf[kk * 2 + jt], va[jt], 0, 0, 0);
      }
#pragma unroll
      for (int jt = 0; jt < 2; ++jt) {
        float bias = qkvb[384 + gch * 32 + jt * 16 + colB];
#pragma unroll
        for (int r = 0; r < 4; ++r)
          st16(sm, vt1_b(jt * 16 + colB, wave * 16 + 4 * grp + r), __float2bfloat16(va[jt][r] + bias));
      }
    }
    if (gch == 0) {  // conv1 (LCE): two 6-frag batches
      float4v acc[2] = {{0,0,0,0},{0,0,0,0}};
      short8 wf[6];
#pragma unroll
      for (int h2 = 0; h2 < 2; ++h2) {
#pragma unroll
        for (int kk = 0; kk < 3; ++kk)
#pragma unroll
          for (int j = 0; j < 2; ++j)
            wf[kk * 2 + j] = glb8(c1wb + (size_t)(j * 16 + colB) * 192 + (h2 * 3 + kk) * 32 + 8 * grp);
#pragma unroll
        for (int kk = 0; kk < 3; ++kk)
#pragma unroll
          for (int j = 0; j < 2; ++j)
            acc[j] = __builtin_amdgcn_mfma_f32_16x16x32_bf16(axw[h2 * 3 + kk], wf[kk * 2 + j], acc[j], 0, 0, 0);
      }
#pragma unroll
      for (int j = 0; j < 2; ++j) {
        int ch = j * 16 + colB;
        if (ch < 24) {
          float bias = c1b[ch];
#pragma unroll
          for (int r = 0; r < 4; ++r) {
            int tok = wave * 16 + 4 * grp + r;
            int i = tok >> 3, jj = tok & 7;
            int hp = (wh * 8 + i + 4) & 255;
            int wpp = (ww * 8 + jj + 4) & 255;
            size_t pix = ((size_t)b << 16) + (hp << 8) + wpp;
            t1[pix * 24 + ch] = acc[j][r] + bias;
          }
        }
      }
    }
    __syncthreads();  // K/V of this chunk visible to all waves

    {  // ---- attention for head h = gch (PS3/STG per-wave private)
      int h = gch;
#pragma unroll
      for (int t = 0; t < 2; ++t)
#pragma unroll
        for (int r = 0; r < 4; ++r)
          st16(sm, ps3_b(wave * 16 + 4 * grp + r, t * 16 + colB), __float2bfloat16(qreg[t * 4 + r]));
      short8 aq = lds8o(sm, ps3_b(wave * 16 + colB, 8 * grp));

      float4v s[4];
#pragma unroll
      for (int nt = 0; nt < 4; ++nt) {
        short8 bk = lds8o(sm, kl1_b(nt * 16 + colB, 8 * grp));
        float4v z = {0, 0, 0, 0};
        s[nt] = __builtin_amdgcn_mfma_f32_16x16x32_bf16(aq, bk, z, 0, 0, 0);
      }
#pragma unroll
      for (int nt = 0; nt < 4; ++nt) {
        int m = nt * 16 + colB;
        int i2 = m >> 3, j2 = m & 7;
        int l2 = region256(wh * 8 + i2) * 3 + region256(ww * 8 + j2);
#pragma unroll
        for (int r = 0; r < 4; ++r) {
          float bias = rpb[((i1r[r] - i2 + 7) * 15 + (j1r[r] - j2 + 7)) * 6 + h];
          s[nt][r] += bias + (l1r[r] != l2 ? -100.f : 0.f);
        }
      }
#pragma unroll
      for (int r = 0; r < 4; ++r) {
        float mx = fmaxf(fmaxf(s[0][r], s[1][r]), fmaxf(s[2][r], s[3][r]));
        mx = fmaxf(mx, __shfl_xor(mx, 1));
        mx = fmaxf(mx, __shfl_xor(mx, 2));
        mx = fmaxf(mx, __shfl_xor(mx, 4));
        mx = fmaxf(mx, __shfl_xor(mx, 8));
        float e0 = __expf(s[0][r] - mx), e1 = __expf(s[1][r] - mx);
        float e2 = __expf(s[2][r] - mx), e3 = __expf(s[3][r] - mx);
        float sum = e0 + e1 + e2 + e3;
        sum += __shfl_xor(sum, 1);
        sum += __shfl_xor(sum, 2);
        sum += __shfl_xor(sum, 4);
        sum += __shfl_xor(sum, 8);
        float inv = 1.f / sum;
        int row = wave * 16 + 4 * grp + r;
        st16(sm, ps3_b(row, 0 * 16 + colB), __float2bfloat16(e0 * inv));
        st16(sm, ps3_b(row, 1 * 16 + colB), __float2bfloat16(e1 * inv));
        st16(sm, ps3_b(row, 2 * 16 + colB), __float2bfloat16(e2 * inv));
        st16(sm, ps3_b(row, 3 * 16 + colB), __float2bfloat16(e3 * inv));
      }
      short8 ap0 = lds8o(sm, ps3_b(wave * 16 + colB, 8 * grp));
      short8 ap1 = lds8o(sm, ps3_b(wave * 16 + colB, 32 + 8 * grp));

      float4v o0 = {0, 0, 0, 0}, o1 = {0, 0, 0, 0};
      o0 = __builtin_amdgcn_mfma_f32_16x16x32_bf16(ap0, lds8o(sm, vt1_b(colB, 8 * grp)), o0, 0, 0, 0);
      o0 = __builtin_amdgcn_mfma_f32_16x16x32_bf16(ap1, lds8o(sm, vt1_b(colB, 32 + 8 * grp)), o0, 0, 0, 0);
      o1 = __builtin_amdgcn_mfma_f32_16x16x32_bf16(ap0, lds8o(sm, vt1_b(16 + colB, 8 * grp)), o1, 0, 0, 0);
      o1 = __builtin_amdgcn_mfma_f32_16x16x32_bf16(ap1, lds8o(sm, vt1_b(16 + colB, 32 + 8 * grp)), o1, 0, 0, 0);
      int ocol = gch * 32;
#pragma unroll
      for (int r = 0; r < 4; ++r) {
        int row = wave * 16 + 4 * grp + r;
        st16(sm, stg_b(row, ocol + colB),      __float2bfloat16(o0[r]));
        st16(sm, stg_b(row, ocol + 16 + colB), __float2bfloat16(o1[r]));
      }
    }
    if (gch != 5) __syncthreads();
  }

  // ---- Phase 4: proj + reverse-shift scatter + residual; 9-frag prefetch batches
  short8 ao[6];
#pragma unroll
  for (int kk = 0; kk < 6; ++kk) ao[kk] = lds8o(sm, stg_b(wave * 16 + colB, kk * 32 + 8 * grp));
  for (int gp = 0; gp < 4; ++gp) {
    float4v acc[3] = {{0,0,0,0},{0,0,0,0},{0,0,0,0}};
#pragma unroll
    for (int half = 0; half < 2; ++half) {
      short8 wfp[9];
#pragma unroll
      for (int kk = 0; kk < 3; ++kk)
#pragma unroll
        for (int j = 0; j < 3; ++j)
          wfp[kk * 3 + j] = glb8(wp + (size_t)((gp * 3 + j) * 16 + colB) * 192 + (half * 3 + kk) * 32 + 8 * grp);
#pragma unroll
      for (int kk = 0; kk < 3; ++kk)
#pragma unroll
        for (int j = 0; j < 3; ++j)
          acc[j] = __builtin_amdgcn_mfma_f32_16x16x32_bf16(ao[half * 3 + kk], wfp[kk * 3 + j], acc[j], 0, 0, 0);
    }
#pragma unroll
    for (int j = 0; j < 3; ++j) {
      int col = (gp * 3 + j) * 16 + colB;
      float bias = projb[col];
#pragma unroll
      for (int r = 0; r < 4; ++r) {
        int n = wave * 16 + 4 * grp + r;
        int i = n >> 3, jj = n & 7;
        int hd2 = (wh * 8 + i + 4) & 255;
        int wd2 = (ww * 8 + jj + 4) & 255;
        size_t p = (((size_t)b << 16) + (hd2 << 8) + wd2) * 192 + col;
        x1out[p] = x[p] + acc[j][r] + bias;
      }
    }
  }
}

// ---------------- FUSED: [LCE conv3x3 + conv1x1-pool (512 blocks)] | [MFMA MLP 64-tok (2048 blocks)] ----------------
// R10: hh shrunk to a 128-col chunk buffer [64][136] (6 fc1/fc2 chunk phases,
// fc2 partials stay in d[3][4] regs). LDS mlp-branch = 25,600 + 17,408 =
// 43,008; conv-branch needs 53,136 -> dynamic 53,248 -> 3 blocks/CU (was 2).
// VGPR ~88 arch + ~48 acc = 136 < (256,3) cap ~168 -> no spill expected.
__global__ __launch_bounds__(256, 3) void k_mlp_lce2(float* __restrict__ x1, const float* __restrict__ g,
                                                     const float* __restrict__ bb, const bf16* __restrict__ w1,
                                                     const float* __restrict__ b1, const bf16* __restrict__ w2,
                                                     const float* __restrict__ b2,
                                                     const float* __restrict__ t1, const float* __restrict__ cw,
                                                     const float* __restrict__ cbia, float* __restrict__ t2,
                                                     const float* __restrict__ c3w, const float* __restrict__ c3b,
                                                     float* __restrict__ s0) {
  extern __shared__ __align__(16) char smu[];
  int tid = threadIdx.x;

  if (blockIdx.x < 512) {
    // ---------- LCE conv3x3 24->24 ----------
    float* halo = (float*)smu;            // 18*18*25 floats = 32,400 B
    float* wlds = (float*)(smu + 32400);  // 5184 floats = 20,736 B
    int bid = blockIdx.x;
    int b = bid >> 8;
    int rem = bid & 255;
    int ty0 = ((rem >> 4) & 15) * 16, tx0 = (rem & 15) * 16;
    for (int idx = tid; idx < 5184; idx += 256) wlds[idx] = cw[idx];
    for (int idx = tid; idx < 18 * 18 * 24; idx += 256) {
      int ch = idx % 24;
      int pp = idx / 24;
      int hy = pp / 18, hx = pp - hy * 18;
      int gy = ty0 + hy - 1, gx = tx0 + hx - 1;
      float v = 0.f;
      if (gy >= 0 && gy < 256 && gx >= 0 && gx < 256)
        v = t1[((size_t)(b << 16) + (gy << 8) + gx) * 24 + ch];
      halo[pp * 25 + ch] = v;
    }
    __syncthreads();
    int py = tid >> 4, px = tid & 15;
    float acc[24];
#pragma unroll
    for (int ro = 0; ro < 24; ++ro) acc[ro] = cbia[ro];
    for (int ky = 0; ky < 3; ++ky) {
      for (int kx = 0; kx < 3; ++kx) {
        int base = ((py + ky) * 18 + px + kx) * 25;
        float inb[24];
#pragma unroll
        for (int ri = 0; ri < 24; ++ri) inb[ri] = halo[base + ri];
        int wo = ky * 3 + kx;
#pragma unroll
        for (int ro = 0; ro < 24; ++ro) {
          float a = acc[ro];
#pragma unroll
          for (int ri = 0; ri < 24; ++ri) a += inb[ri] * wlds[ro * 216 + ri * 9 + wo];
          acc[ro] = a;
        }
      }
    }
    size_t pix = (size_t)(b << 16) + ((ty0 + py) << 8) + tx0 + px;
#pragma unroll
    for (int ro = 0; ro < 24; ++ro) t2[pix * 24 + ro] = acc[ro];

    // ---------- conv1x1 24->192 + LeakyReLU pool partials ----------
    __syncthreads();
    float* t2l = (float*)smu;            // [256][28] floats = 28,672 B
#pragma unroll
    for (int ro = 0; ro < 24; ++ro) t2l[tid * 28 + ro] = acc[ro];
    __syncthreads();
    if (tid < 192) {
      float wr3[24];
#pragma unroll
      for (int i2 = 0; i2 < 24; ++i2) wr3[i2] = c3w[tid * 24 + i2];
      float b3 = c3b[tid];
      float ps = 0.f;
      for (int p = 0; p < 256; ++p) {
        const float4v* rp = reinterpret_cast<const float4v*>(&t2l[p * 28]);
        float a = b3;
#pragma unroll
        for (int v = 0; v < 6; ++v) {
          float4v q = rp[v];
          a += q[0] * wr3[v * 4] + q[1] * wr3[v * 4 + 1] + q[2] * wr3[v * 4 + 2] + q[3] * wr3[v * 4 + 3];
        }
        ps += (a < 0.f) ? 0.2f * a : a;
      }
      atomicAdd(&s0[b * 192 + tid], ps);
    }
    return;
  }

  // ---------- MFMA MLP: 64 tokens, LN2 + fc1 + GELU + fc2 + residual ----------
  // xl @0: [64][200] bf16 (25,600 B); hh @25600: [64][136] bf16 (17,408 B)
  bf16 (*xl)[200] = reinterpret_cast<bf16(*)[200]>(smu);
  bf16 (*hh)[136] = reinterpret_cast<bf16(*)[136]>(smu + 25600);
  int wave = tid >> 6, lane = tid & 63;
  int colB = lane & 15, grp = lane >> 4;
  size_t tokbase = (size_t)(blockIdx.x - 512) * 64;

  for (int t = wave; t < 64; t += 4) {
    const float* xr = x1 + (tokbase + t) * 192;
    float v0 = xr[lane], v1 = xr[lane + 64], v2 = xr[lane + 128];
    float s = v0 + v1 + v2;
    for (int o = 32; o > 0; o >>= 1) s += __shfl_down(s, o);
    s = __shfl(s, 0);
    float m = s * (1.f / 192.f);
    float d0 = v0 - m, d1 = v1 - m, d2 = v2 - m;
    float qq = d0 * d0 + d1 * d1 + d2 * d2;
    for (int o = 32; o > 0; o >>= 1) qq += __shfl_down(qq, o);
    qq = __shfl(qq, 0);
    float inv = rsqrtf(qq * (1.f / 192.f) + 1e-5f);
    xl[t][lane]       = __float2bfloat16(d0 * inv * g[lane]       + bb[lane]);
    xl[t][lane + 64]  = __float2bfloat16(d1 * inv * g[lane + 64]  + bb[lane + 64]);
    xl[t][lane + 128] = __float2bfloat16(d2 * inv * g[lane + 128] + bb[lane + 128]);
  }
  __syncthreads();

  // A-frags for token-tiles 0,1 cached in regs; tiles 2,3 read from LDS per use
  short8 a1f[6][2];
#pragma unroll
  for (int kk = 0; kk < 6; ++kk) {
    a1f[kk][0] = lds8(&xl[colB][kk * 32 + 8 * grp]);
    a1f[kk][1] = lds8(&xl[16 + colB][kk * 32 + 8 * grp]);
  }

  float4v d[3][4];
#pragma unroll
  for (int j = 0; j < 3; ++j)
#pragma unroll
    for (int tt = 0; tt < 4; ++tt) d[j][tt] = (float4v){0, 0, 0, 0};
  int ntb = wave * 3;

  for (int ch = 0; ch < 6; ++ch) {  // 128-col fc1 chunk / 128-K fc2 chunk
    if (ch) __syncthreads();        // prior fc2 reads of hh complete before overwrite
    // fc1 chunk: 8 N-tiles (128 cols), 2 per wave, each over 4 token-tiles
    for (int nn = 0; nn < 2; ++nn) {
      int ntl = wave * 2 + nn;                // local tile 0..7
      int colg = ch * 128 + ntl * 16 + colB;  // global fc1 col
      short8 wf1[6];
#pragma unroll
      for (int kk = 0; kk < 6; ++kk)
        wf1[kk] = glb8(w1 + (size_t)colg * 192 + kk * 32 + 8 * grp);
      float4v c0 = {0,0,0,0}, c1 = {0,0,0,0}, c2 = {0,0,0,0}, c3 = {0,0,0,0};
#pragma unroll
      for (int kk = 0; kk < 6; ++kk) {
        c0 = __builtin_amdgcn_mfma_f32_16x16x32_bf16(a1f[kk][0], wf1[kk], c0, 0, 0, 0);
        c1 = __builtin_amdgcn_mfma_f32_16x16x32_bf16(a1f[kk][1], wf1[kk], c1, 0, 0, 0);
        c2 = __builtin_amdgcn_mfma_f32_16x16x32_bf16(lds8(&xl[32 + colB][kk * 32 + 8 * grp]), wf1[kk], c2, 0, 0, 0);
        c3 = __builtin_amdgcn_mfma_f32_16x16x32_bf16(lds8(&xl[48 + colB][kk * 32 + 8 * grp]), wf1[kk], c3, 0, 0, 0);
      }
      float bias = b1[colg];
      int coll = ntl * 16 + colB;  // local col 0..127
#pragma unroll
      for (int r = 0; r < 4; ++r) {
        float v0 = c0[r] + bias;
        float v1 = c1[r] + bias;
        float v2 = c2[r] + bias;
        float v3 = c3[r] + bias;
        v0 = v0 * 0.5f * (1.f + erff(v0 * 0.70710678118654752f));
        v1 = v1 * 0.5f * (1.f + erff(v1 * 0.70710678118654752f));
        v2 = v2 * 0.5f * (1.f + erff(v2 * 0.70710678118654752f));
        v3 = v3 * 0.5f * (1.f + erff(v3 * 0.70710678118654752f));
        hh[4 * grp + r][coll]      = __float2bfloat16(v0);
        hh[16 + 4 * grp + r][coll] = __float2bfloat16(v1);
        hh[32 + 4 * grp + r][coll] = __float2bfloat16(v2);
        hh[48 + 4 * grp + r][coll] = __float2bfloat16(v3);
      }
    }
    __syncthreads();
    // fc2 partial over this chunk's 128 K, all 4 token-tiles
    for (int kk2 = 0; kk2 < 4; ++kk2) {
      int kol = kk2 * 32 + 8 * grp;   // local K col 0..127
      int kog = ch * 128 + kol;       // global K col
      short8 wf2[3];
#pragma unroll
      for (int j = 0; j < 3; ++j)
        wf2[j] = glb8(w2 + (size_t)((ntb + j) * 16 + colB) * 768 + kog);
      short8 h0 = lds8(&hh[colB][kol]);
      short8 h1 = lds8(&hh[16 + colB][kol]);
      short8 h2 = lds8(&hh[32 + colB][kol]);
      short8 h3 = lds8(&hh[48 + colB][kol]);
#pragma unroll
      for (int j = 0; j < 3; ++j) {
        d[j][0] = __builtin_amdgcn_mfma_f32_16x16x32_bf16(h0, wf2[j], d[j][0], 0, 0, 0);
        d[j][1] = __builtin_amdgcn_mfma_f32_16x16x32_bf16(h1, wf2[j], d[j][1], 0, 0, 0);
        d[j][2] = __builtin_amdgcn_mfma_f32_16x16x32_bf16(h2, wf2[j], d[j][2], 0, 0, 0);
        d[j][3] = __builtin_amdgcn_mfma_f32_16x16x32_bf16(h3, wf2[j], d[j][3], 0, 0, 0);
      }
    }
  }

#pragma unroll
  for (int j = 0; j < 3; ++j) {
    int col = (ntb + j) * 16 + colB;
    float bias = b2[col];
#pragma unroll
    for (int tt = 0; tt < 4; ++tt) {
#pragma unroll
      for (int r = 0; r < 4; ++r) {
        size_t p = (tokbase + tt * 16 + 4 * grp + r) * 192 + col;
        x1[p] += d[j][tt][r] + bias;
      }
    }
  }
}

// ---------------- FUSED: SE gate + conv1x1 recompute + out += y*gate ----------------
__global__ __launch_bounds__(192) void k_final3(float* __restrict__ out, const float* __restrict__ t2,
                                                const float* __restrict__ c3w, const float* __restrict__ c3b,
                                                const float* __restrict__ s0, const float* __restrict__ w1se,
                                                const float* __restrict__ w2se) {
  __shared__ float mean[192];
  __shared__ float tt[24];
  __shared__ __align__(16) float t2l[64 * 24];
  int b = blockIdx.x >> 10;
  int chunk = blockIdx.x & 1023;
  int tid = threadIdx.x;  // 0..191
  mean[tid] = s0[b * 192 + tid] * (1.f / 65536.f);
  size_t pix0 = (size_t)b * 65536 + chunk * 64;
  for (int idx = tid; idx < 1536; idx += 192) t2l[idx] = t2[pix0 * 24 + idx];
  __syncthreads();
  if (tid < 24) {
    float a = 0.f;
    for (int c = 0; c < 192; ++c) a += mean[c] * w1se[tid * 192 + c];
    tt[tid] = fmaxf(a, 0.f);
  }
  __syncthreads();
  float a = 0.f;
#pragma unroll
  for (int r = 0; r < 24; ++r) a += tt[r] * w2se[tid * 24 + r];
  float gate = 1.f / (1.f + expf(-a));

  float wr3[24];
#pragma unroll
  for (int i = 0; i < 24; ++i) wr3[i] = c3w[tid * 24 + i];
  float b3 = c3b[tid];
  for (int p = 0; p < 64; ++p) {
    const float4v* rp = reinterpret_cast<const float4v*>(&t2l[p * 24]);
    float acc = b3;
#pragma unroll
    for (int v = 0; v < 6; ++v) {
      float4v q = rp[v];
      acc += q[0] * wr3[v * 4] + q[1] * wr3[v * 4 + 1] + q[2] * wr3[v * 4 + 2] + q[3] * wr3[v * 4 + 3];
    }
    if (acc < 0.f) acc *= 0.2f;
    out[(pix0 + p) * 192 + tid] += acc * gate;
  }
}

extern "C" void kernel_launch(void* const* d_in, const int* in_sizes, int n_in,
                              void* d_out, int out_size, void* d_ws, size_t ws_size,
                              hipStream_t stream) {
  const float* x     = (const float*)d_in[0];
  const float* n1g   = (const float*)d_in[1];
  const float* n1b   = (const float*)d_in[2];
  const float* qkvw  = (const float*)d_in[3];
  const float* qkvb  = (const float*)d_in[4];
  const float* rpb   = (const float*)d_in[5];
  const float* projw = (const float*)d_in[6];
  const float* projb = (const float*)d_in[7];
  const float* n2g   = (const float*)d_in[8];
  const float* n2b   = (const float*)d_in[9];
  const float* w1    = (const float*)d_in[10];
  const float* b1    = (const float*)d_in[11];
  const float* w2    = (const float*)d_in[12];
  const float* b2    = (const float*)d_in[13];
  const float* c1w   = (const float*)d_in[14];
  const float* c1b   = (const float*)d_in[15];
  const float* c2w   = (const float*)d_in[16];
  const float* c2b   = (const float*)d_in[17];
  const float* c3w   = (const float*)d_in[18];
  const float* c3b   = (const float*)d_in[19];
  const float* sfc1  = (const float*)d_in[20];
  const float* sfc2  = (const float*)d_in[21];
  float* out = (float*)d_out;

  if (ws_size < WS_NEEDED) return;

  char* ws = (char*)d_ws;
  float* t1   = (float*)(ws + OFF_T1);
  float* t2   = (float*)(ws + OFF_T2);
  float* s0   = (float*)(ws + OFF_S0);
  bf16*  wqkv = (bf16*)(ws + OFF_WQKV);
  bf16*  wprj = (bf16*)(ws + OFF_WPRJ);
  bf16*  wfc1 = (bf16*)(ws + OFF_WFC1);
  bf16*  wfc2 = (bf16*)(ws + OFF_WFC2);
  bf16*  c1wb = (bf16*)(ws + OFF_C1WB);

  hipFuncSetAttribute((const void*)k_mlp_lce2, hipFuncAttributeMaxDynamicSharedMemorySize, 53248);

  // weight converts + c1wb zero-pad + s0 zero, one dispatch
  k_f2b_all<<<1754, 256, 0, stream>>>(qkvw, projw, w1, w2, c1w,
                                      wqkv, wprj, wfc1, wfc2, c1wb, s0);

  // fused attention + LN1 + LCE conv1 (t1), writes x1 into d_out
  k_attn2<<<2048, 256, 0, stream>>>(x, n1g, n1b, wqkv, qkvb, rpb, wprj, projb,
                                    c1wb, c1b, t1, out);
  // FUSED: LCE conv3x3 + pool (blocks 0..511) | 64-token MLP (blocks 512..2559)
  k_mlp_lce2<<<2560, 256, 53248, stream>>>(out, n2g, n2b, wfc1, b1, wfc2, b2,
                                           t1, c2w, c2b, t2, c3w, c3b, s0);
  // FUSED: SE gate + conv1x1 recompute + out += y*gate
  k_final3<<<2048, 192, 0, stream>>>(out, t2, c3w, c3b, s0, sfc1, sfc2);
}

// Round 11
// 886.246 us; speedup vs baseline: 1.1147x; 1.1147x over previous
//
#include <hip/hip_runtime.h>
#include <hip/hip_bf16.h>

using bf16 = __hip_bfloat16;
typedef __attribute__((ext_vector_type(8))) short short8;
typedef __attribute__((ext_vector_type(4))) float float4v;

constexpr int NTOK = 131072;  // 2*256*256

// ---------------- workspace layout (bytes) ----------------
constexpr size_t OFF_T1   = 50331648;    // f32  [131072][24]     12,582,912
constexpr size_t OFF_T2   = 62914560;    // f32  [131072][24]     12,582,912
constexpr size_t OFF_S0   = 75497472;    // f32  [2][192]
constexpr size_t OFF_WQKV = 75500544;    // bf16 [576][192]       221,184
constexpr size_t OFF_WPRJ = 75721728;    // bf16 [192][192]        73,728
constexpr size_t OFF_WFC1 = 75795456;    // bf16 [768][192]       294,912
constexpr size_t OFF_WFC2 = 76090368;    // bf16 [192][768]       294,912
constexpr size_t OFF_C1WB = 76385280;    // bf16 [32][192]         12,288 (rows 24..31 zero)
constexpr size_t WS_NEEDED = 76397568;

__device__ __forceinline__ int region256(int t) { return t < 248 ? 0 : (t < 252 ? 1 : 2); }

__device__ __forceinline__ short8 lds8(const bf16* p) {
  return *reinterpret_cast<const short8*>(p);
}
__device__ __forceinline__ short8 glb8(const bf16* p) {
  return *reinterpret_cast<const short8*>(p);
}

// ---------------- fp32 -> bf16 weight convert + zero-init (one dispatch) ----------------
__global__ __launch_bounds__(256) void k_f2b_all(const float* __restrict__ qkvw, const float* __restrict__ projw,
                                                 const float* __restrict__ w1, const float* __restrict__ w2,
                                                 const float* __restrict__ c1w,
                                                 bf16* __restrict__ wqkv, bf16* __restrict__ wprj,
                                                 bf16* __restrict__ wfc1, bf16* __restrict__ wfc2,
                                                 bf16* __restrict__ c1wb, float* __restrict__ s0) {
  int i = blockIdx.x * 256 + threadIdx.x;
  if (i < 110592) { wqkv[i] = __float2bfloat16(qkvw[i]); return; }
  i -= 110592;
  if (i < 36864) { wprj[i] = __float2bfloat16(projw[i]); return; }
  i -= 36864;
  if (i < 147456) { wfc1[i] = __float2bfloat16(w1[i]); return; }
  i -= 147456;
  if (i < 147456) { wfc2[i] = __float2bfloat16(w2[i]); return; }
  i -= 147456;
  if (i < 4608) { c1wb[i] = __float2bfloat16(c1w[i]); return; }
  i -= 4608;
  if (i < 1536) { c1wb[4608 + i] = __float2bfloat16(0.f); return; }  // pad rows 24..31
  i -= 1536;
  if (i < 384) s0[i] = 0.f;
}

// ---------------- chunked fused attention (+ LCE conv1) ----------------
// FINAL CONFIG (R9, best measured: attn 374 us, total 884 us).
// Allocator model (R8/R10 evidence): reported arch-VGPR + MFMA accumulators
// share the unified 128-per-wave file at (256,4); this kernel needs ~84 arch
// + ~44 acc, so (256,4) forces arch=64 + scratch spill (FETCH 102->156 MB).
// (256,3) cap ~168 fits cleanly. Prefetch@3blk (374) > no-prefetch@4blk (388).
__device__ __forceinline__ int stg_b(int r, int c) { return (r * 384 + c * 2) ^ ((r & 7) << 4); }
__device__ __forceinline__ int kl1_b(int r, int c) { return 24576 + ((r * 64 + c * 2) ^ ((r & 7) << 4)); }
__device__ __forceinline__ int vt1_b(int r, int c) { return 28672 + ((r * 128 + c * 2) ^ ((r & 7) << 4)); }
__device__ __forceinline__ int ps3_b(int r, int c) { return 32768 + ((r * 128 + c * 2) ^ ((r & 7) << 4)); }

__device__ __forceinline__ short8 lds8o(const char* sm, int byteoff) {
  return *reinterpret_cast<const short8*>(sm + byteoff);
}
__device__ __forceinline__ void st16(char* sm, int byteoff, bf16 v) {
  *reinterpret_cast<bf16*>(sm + byteoff) = v;
}

__global__ __launch_bounds__(256, 3) void k_attn2(const float* __restrict__ x, const float* __restrict__ g,
                                                  const float* __restrict__ bb, const bf16* __restrict__ wq,
                                                  const float* __restrict__ qkvb, const float* __restrict__ rpb,
                                                  const bf16* __restrict__ wp, const float* __restrict__ projb,
                                                  const bf16* __restrict__ c1wb, const float* __restrict__ c1b,
                                                  float* __restrict__ t1, float* __restrict__ x1out) {
  __shared__ char sm[40960];

  int win = blockIdx.x;
  int b = win >> 10;
  int wrem = win & 1023;
  int wh = wrem >> 5, ww = wrem & 31;
  int tid = threadIdx.x;
  int wave = tid >> 6, lane = tid & 63;
  int colB = lane & 15, grp = lane >> 4;
  const float scale = 0.17677669529663687f;  // 1/sqrt(32)

  // ---- Phase 1: LN over this wave's 16 tokens (gather with roll -4) -> staging (wave-private rows)
  for (int t = 0; t < 16; ++t) {
    int tok = wave * 16 + t;
    int i = tok >> 3, j = tok & 7;
    int hp = (wh * 8 + i + 4) & 255;
    int wpp = (ww * 8 + j + 4) & 255;
    const float* xr = x + (((size_t)b << 16) + (hp << 8) + wpp) * 192;
    float v0 = xr[lane], v1 = xr[lane + 64], v2 = xr[lane + 128];
    float s = v0 + v1 + v2;
    for (int o = 32; o > 0; o >>= 1) s += __shfl_down(s, o);
    s = __shfl(s, 0);
    float m = s * (1.f / 192.f);
    float d0 = v0 - m, d1 = v1 - m, d2 = v2 - m;
    float q = d0 * d0 + d1 * d1 + d2 * d2;
    for (int o = 32; o > 0; o >>= 1) q += __shfl_down(q, o);
    q = __shfl(q, 0);
    float inv = rsqrtf(q * (1.f / 192.f) + 1e-5f);
    st16(sm, stg_b(tok, lane),       __float2bfloat16(d0 * inv * g[lane]       + bb[lane]));
    st16(sm, stg_b(tok, lane + 64),  __float2bfloat16(d1 * inv * g[lane + 64]  + bb[lane + 64]));
    st16(sm, stg_b(tok, lane + 128), __float2bfloat16(d2 * inv * g[lane + 128] + bb[lane + 128]));
  }

  short8 axw[6];
#pragma unroll
  for (int kk = 0; kk < 6; ++kk) axw[kk] = lds8o(sm, stg_b(wave * 16 + colB, kk * 32 + 8 * grp));

  int l1r[4], i1r[4], j1r[4];
#pragma unroll
  for (int r = 0; r < 4; ++r) {
    int n = wave * 16 + 4 * grp + r;
    i1r[r] = n >> 3; j1r[r] = n & 7;
    l1r[r] = region256(wh * 8 + i1r[r]) * 3 + region256(ww * 8 + j1r[r]);
  }

  for (int gch = 0; gch < 6; ++gch) {  // chunk = head gch = qkv cols 32g..32g+31
    float qreg[8];
    {  // Q: two 6-frag prefetch batches (24 VGPR transient, reused)
      float4v qa[2] = {{0,0,0,0},{0,0,0,0}};
      short8 wf[6];
#pragma unroll
      for (int h2 = 0; h2 < 2; ++h2) {
#pragma unroll
        for (int kk = 0; kk < 3; ++kk)
#pragma unroll
          for (int jt = 0; jt < 2; ++jt)
            wf[kk * 2 + jt] = glb8(wq + (size_t)(gch * 32 + jt * 16 + colB) * 192 + (h2 * 3 + kk) * 32 + 8 * grp);
#pragma unroll
        for (int kk = 0; kk < 3; ++kk)
#pragma unroll
          for (int jt = 0; jt < 2; ++jt)
            qa[jt] = __builtin_amdgcn_mfma_f32_16x16x32_bf16(axw[h2 * 3 + kk], wf[kk * 2 + jt], qa[jt], 0, 0, 0);
      }
#pragma unroll
      for (int jt = 0; jt < 2; ++jt) {
        float bias = qkvb[gch * 32 + jt * 16 + colB];
#pragma unroll
        for (int r = 0; r < 4; ++r) qreg[jt * 4 + r] = (qa[jt][r] + bias) * scale;
      }
    }
    {  // K -> KL1: two 6-frag batches
      float4v ka[2] = {{0,0,0,0},{0,0,0,0}};
      short8 wf[6];
#pragma unroll
      for (int h2 = 0; h2 < 2; ++h2) {
#pragma unroll
        for (int kk = 0; kk < 3; ++kk)
#pragma unroll
          for (int jt = 0; jt < 2; ++jt)
            wf[kk * 2 + jt] = glb8(wq + (size_t)(192 + gch * 32 + jt * 16 + colB) * 192 + (h2 * 3 + kk) * 32 + 8 * grp);
#pragma unroll
        for (int kk = 0; kk < 3; ++kk)
#pragma unroll
          for (int jt = 0; jt < 2; ++jt)
            ka[jt] = __builtin_amdgcn_mfma_f32_16x16x32_bf16(axw[h2 * 3 + kk], wf[kk * 2 + jt], ka[jt], 0, 0, 0);
      }
#pragma unroll
      for (int jt = 0; jt < 2; ++jt) {
        float bias = qkvb[192 + gch * 32 + jt * 16 + colB];
#pragma unroll
        for (int r = 0; r < 4; ++r)
          st16(sm, kl1_b(wave * 16 + 4 * grp + r, jt * 16 + colB), __float2bfloat16(ka[jt][r] + bias));
      }
    }
    {  // V -> VT1 (transposed): two 6-frag batches
      float4v va[2] = {{0,0,0,0},{0,0,0,0}};
      short8 wf[6];
#pragma unroll
      for (int h2 = 0; h2 < 2; ++h2) {
#pragma unroll
        for (int kk = 0; kk < 3; ++kk)
#pragma unroll
          for (int jt = 0; jt < 2; ++jt)
            wf[kk * 2 + jt] = glb8(wq + (size_t)(384 + gch * 32 + jt * 16 + colB) * 192 + (h2 * 3 + kk) * 32 + 8 * grp);
#pragma unroll
        for (int kk = 0; kk < 3; ++kk)
#pragma unroll
          for (int jt = 0; jt < 2; ++jt)
            va[jt] = __builtin_amdgcn_mfma_f32_16x16x32_bf16(axw[h2 * 3 + kk], wf[kk * 2 + jt], va[jt], 0, 0, 0);
      }
#pragma unroll
      for (int jt = 0; jt < 2; ++jt) {
        float bias = qkvb[384 + gch * 32 + jt * 16 + colB];
#pragma unroll
        for (int r = 0; r < 4; ++r)
          st16(sm, vt1_b(jt * 16 + colB, wave * 16 + 4 * grp + r), __float2bfloat16(va[jt][r] + bias));
      }
    }
    if (gch == 0) {  // conv1 (LCE): two 6-frag batches
      float4v acc[2] = {{0,0,0,0},{0,0,0,0}};
      short8 wf[6];
#pragma unroll
      for (int h2 = 0; h2 < 2; ++h2) {
#pragma unroll
        for (int kk = 0; kk < 3; ++kk)
#pragma unroll
          for (int j = 0; j < 2; ++j)
            wf[kk * 2 + j] = glb8(c1wb + (size_t)(j * 16 + colB) * 192 + (h2 * 3 + kk) * 32 + 8 * grp);
#pragma unroll
        for (int kk = 0; kk < 3; ++kk)
#pragma unroll
          for (int j = 0; j < 2; ++j)
            acc[j] = __builtin_amdgcn_mfma_f32_16x16x32_bf16(axw[h2 * 3 + kk], wf[kk * 2 + j], acc[j], 0, 0, 0);
      }
#pragma unroll
      for (int j = 0; j < 2; ++j) {
        int ch = j * 16 + colB;
        if (ch < 24) {
          float bias = c1b[ch];
#pragma unroll
          for (int r = 0; r < 4; ++r) {
            int tok = wave * 16 + 4 * grp + r;
            int i = tok >> 3, jj = tok & 7;
            int hp = (wh * 8 + i + 4) & 255;
            int wpp = (ww * 8 + jj + 4) & 255;
            size_t pix = ((size_t)b << 16) + (hp << 8) + wpp;
            t1[pix * 24 + ch] = acc[j][r] + bias;
          }
        }
      }
    }
    __syncthreads();  // K/V of this chunk visible to all waves

    {  // ---- attention for head h = gch (PS3/STG per-wave private)
      int h = gch;
#pragma unroll
      for (int t = 0; t < 2; ++t)
#pragma unroll
        for (int r = 0; r < 4; ++r)
          st16(sm, ps3_b(wave * 16 + 4 * grp + r, t * 16 + colB), __float2bfloat16(qreg[t * 4 + r]));
      short8 aq = lds8o(sm, ps3_b(wave * 16 + colB, 8 * grp));

      float4v s[4];
#pragma unroll
      for (int nt = 0; nt < 4; ++nt) {
        short8 bk = lds8o(sm, kl1_b(nt * 16 + colB, 8 * grp));
        float4v z = {0, 0, 0, 0};
        s[nt] = __builtin_amdgcn_mfma_f32_16x16x32_bf16(aq, bk, z, 0, 0, 0);
      }
#pragma unroll
      for (int nt = 0; nt < 4; ++nt) {
        int m = nt * 16 + colB;
        int i2 = m >> 3, j2 = m & 7;
        int l2 = region256(wh * 8 + i2) * 3 + region256(ww * 8 + j2);
#pragma unroll
        for (int r = 0; r < 4; ++r) {
          float bias = rpb[((i1r[r] - i2 + 7) * 15 + (j1r[r] - j2 + 7)) * 6 + h];
          s[nt][r] += bias + (l1r[r] != l2 ? -100.f : 0.f);
        }
      }
#pragma unroll
      for (int r = 0; r < 4; ++r) {
        float mx = fmaxf(fmaxf(s[0][r], s[1][r]), fmaxf(s[2][r], s[3][r]));
        mx = fmaxf(mx, __shfl_xor(mx, 1));
        mx = fmaxf(mx, __shfl_xor(mx, 2));
        mx = fmaxf(mx, __shfl_xor(mx, 4));
        mx = fmaxf(mx, __shfl_xor(mx, 8));
        float e0 = __expf(s[0][r] - mx), e1 = __expf(s[1][r] - mx);
        float e2 = __expf(s[2][r] - mx), e3 = __expf(s[3][r] - mx);
        float sum = e0 + e1 + e2 + e3;
        sum += __shfl_xor(sum, 1);
        sum += __shfl_xor(sum, 2);
        sum += __shfl_xor(sum, 4);
        sum += __shfl_xor(sum, 8);
        float inv = 1.f / sum;
        int row = wave * 16 + 4 * grp + r;
        st16(sm, ps3_b(row, 0 * 16 + colB), __float2bfloat16(e0 * inv));
        st16(sm, ps3_b(row, 1 * 16 + colB), __float2bfloat16(e1 * inv));
        st16(sm, ps3_b(row, 2 * 16 + colB), __float2bfloat16(e2 * inv));
        st16(sm, ps3_b(row, 3 * 16 + colB), __float2bfloat16(e3 * inv));
      }
      short8 ap0 = lds8o(sm, ps3_b(wave * 16 + colB, 8 * grp));
      short8 ap1 = lds8o(sm, ps3_b(wave * 16 + colB, 32 + 8 * grp));

      float4v o0 = {0, 0, 0, 0}, o1 = {0, 0, 0, 0};
      o0 = __builtin_amdgcn_mfma_f32_16x16x32_bf16(ap0, lds8o(sm, vt1_b(colB, 8 * grp)), o0, 0, 0, 0);
      o0 = __builtin_amdgcn_mfma_f32_16x16x32_bf16(ap1, lds8o(sm, vt1_b(colB, 32 + 8 * grp)), o0, 0, 0, 0);
      o1 = __builtin_amdgcn_mfma_f32_16x16x32_bf16(ap0, lds8o(sm, vt1_b(16 + colB, 8 * grp)), o1, 0, 0, 0);
      o1 = __builtin_amdgcn_mfma_f32_16x16x32_bf16(ap1, lds8o(sm, vt1_b(16 + colB, 32 + 8 * grp)), o1, 0, 0, 0);
      int ocol = gch * 32;
#pragma unroll
      for (int r = 0; r < 4; ++r) {
        int row = wave * 16 + 4 * grp + r;
        st16(sm, stg_b(row, ocol + colB),      __float2bfloat16(o0[r]));
        st16(sm, stg_b(row, ocol + 16 + colB), __float2bfloat16(o1[r]));
      }
    }
    if (gch != 5) __syncthreads();
  }

  // ---- Phase 4: proj + reverse-shift scatter + residual; 9-frag prefetch batches
  short8 ao[6];
#pragma unroll
  for (int kk = 0; kk < 6; ++kk) ao[kk] = lds8o(sm, stg_b(wave * 16 + colB, kk * 32 + 8 * grp));
  for (int gp = 0; gp < 4; ++gp) {
    float4v acc[3] = {{0,0,0,0},{0,0,0,0},{0,0,0,0}};
#pragma unroll
    for (int half = 0; half < 2; ++half) {
      short8 wfp[9];
#pragma unroll
      for (int kk = 0; kk < 3; ++kk)
#pragma unroll
        for (int j = 0; j < 3; ++j)
          wfp[kk * 3 + j] = glb8(wp + (size_t)((gp * 3 + j) * 16 + colB) * 192 + (half * 3 + kk) * 32 + 8 * grp);
#pragma unroll
      for (int kk = 0; kk < 3; ++kk)
#pragma unroll
        for (int j = 0; j < 3; ++j)
          acc[j] = __builtin_amdgcn_mfma_f32_16x16x32_bf16(ao[half * 3 + kk], wfp[kk * 3 + j], acc[j], 0, 0, 0);
    }
#pragma unroll
    for (int j = 0; j < 3; ++j) {
      int col = (gp * 3 + j) * 16 + colB;
      float bias = projb[col];
#pragma unroll
      for (int r = 0; r < 4; ++r) {
        int n = wave * 16 + 4 * grp + r;
        int i = n >> 3, jj = n & 7;
        int hd2 = (wh * 8 + i + 4) & 255;
        int wd2 = (ww * 8 + jj + 4) & 255;
        size_t p = (((size_t)b << 16) + (hd2 << 8) + wd2) * 192 + col;
        x1out[p] = x[p] + acc[j][r] + bias;
      }
    }
  }
}

// ---------------- FUSED: [LCE conv3x3 + conv1x1-pool (512 blocks)] | [MFMA MLP 64-tok (2048 blocks)] ----------------
// R9 config (best measured): 64-token MLP, reuse-4 per weight fragment,
// fc1/fc2 batch-loads, hh full 768 cols [64][392], 2 blocks/CU.
// (R10's 128-col chunking regressed: 12 barriers for +1 block/CU.)
__global__ __launch_bounds__(256, 2) void k_mlp_lce2(float* __restrict__ x1, const float* __restrict__ g,
                                                     const float* __restrict__ bb, const bf16* __restrict__ w1,
                                                     const float* __restrict__ b1, const bf16* __restrict__ w2,
                                                     const float* __restrict__ b2,
                                                     const float* __restrict__ t1, const float* __restrict__ cw,
                                                     const float* __restrict__ cbia, float* __restrict__ t2,
                                                     const float* __restrict__ c3w, const float* __restrict__ c3b,
                                                     float* __restrict__ s0) {
  extern __shared__ __align__(16) char smu[];
  int tid = threadIdx.x;

  if (blockIdx.x < 512) {
    // ---------- LCE conv3x3 24->24 ----------
    float* halo = (float*)smu;            // 18*18*25 floats = 32,400 B
    float* wlds = (float*)(smu + 32400);  // 5184 floats = 20,736 B
    int bid = blockIdx.x;
    int b = bid >> 8;
    int rem = bid & 255;
    int ty0 = ((rem >> 4) & 15) * 16, tx0 = (rem & 15) * 16;
    for (int idx = tid; idx < 5184; idx += 256) wlds[idx] = cw[idx];
    for (int idx = tid; idx < 18 * 18 * 24; idx += 256) {
      int ch = idx % 24;
      int pp = idx / 24;
      int hy = pp / 18, hx = pp - hy * 18;
      int gy = ty0 + hy - 1, gx = tx0 + hx - 1;
      float v = 0.f;
      if (gy >= 0 && gy < 256 && gx >= 0 && gx < 256)
        v = t1[((size_t)(b << 16) + (gy << 8) + gx) * 24 + ch];
      halo[pp * 25 + ch] = v;
    }
    __syncthreads();
    int py = tid >> 4, px = tid & 15;
    float acc[24];
#pragma unroll
    for (int ro = 0; ro < 24; ++ro) acc[ro] = cbia[ro];
    for (int ky = 0; ky < 3; ++ky) {
      for (int kx = 0; kx < 3; ++kx) {
        int base = ((py + ky) * 18 + px + kx) * 25;
        float inb[24];
#pragma unroll
        for (int ri = 0; ri < 24; ++ri) inb[ri] = halo[base + ri];
        int wo = ky * 3 + kx;
#pragma unroll
        for (int ro = 0; ro < 24; ++ro) {
          float a = acc[ro];
#pragma unroll
          for (int ri = 0; ri < 24; ++ri) a += inb[ri] * wlds[ro * 216 + ri * 9 + wo];
          acc[ro] = a;
        }
      }
    }
    size_t pix = (size_t)(b << 16) + ((ty0 + py) << 8) + tx0 + px;
#pragma unroll
    for (int ro = 0; ro < 24; ++ro) t2[pix * 24 + ro] = acc[ro];

    // ---------- conv1x1 24->192 + LeakyReLU pool partials ----------
    __syncthreads();
    float* t2l = (float*)smu;            // [256][28] floats = 28,672 B
#pragma unroll
    for (int ro = 0; ro < 24; ++ro) t2l[tid * 28 + ro] = acc[ro];
    __syncthreads();
    if (tid < 192) {
      float wr3[24];
#pragma unroll
      for (int i2 = 0; i2 < 24; ++i2) wr3[i2] = c3w[tid * 24 + i2];
      float b3 = c3b[tid];
      float ps = 0.f;
      for (int p = 0; p < 256; ++p) {
        const float4v* rp = reinterpret_cast<const float4v*>(&t2l[p * 28]);
        float a = b3;
#pragma unroll
        for (int v = 0; v < 6; ++v) {
          float4v q = rp[v];
          a += q[0] * wr3[v * 4] + q[1] * wr3[v * 4 + 1] + q[2] * wr3[v * 4 + 2] + q[3] * wr3[v * 4 + 3];
        }
        ps += (a < 0.f) ? 0.2f * a : a;
      }
      atomicAdd(&s0[b * 192 + tid], ps);
    }
    return;
  }

  // ---------- MFMA MLP: 64 tokens, LN2 + fc1 + GELU + fc2 + residual ----------
  // xl @0: [64][200] bf16 (25,600 B); hh @25600: [64][392] bf16 (50,176 B)
  bf16 (*xl)[200] = reinterpret_cast<bf16(*)[200]>(smu);
  bf16 (*hh)[392] = reinterpret_cast<bf16(*)[392]>(smu + 25600);
  int wave = tid >> 6, lane = tid & 63;
  int colB = lane & 15, grp = lane >> 4;
  size_t tokbase = (size_t)(blockIdx.x - 512) * 64;

  for (int t = wave; t < 64; t += 4) {
    const float* xr = x1 + (tokbase + t) * 192;
    float v0 = xr[lane], v1 = xr[lane + 64], v2 = xr[lane + 128];
    float s = v0 + v1 + v2;
    for (int o = 32; o > 0; o >>= 1) s += __shfl_down(s, o);
    s = __shfl(s, 0);
    float m = s * (1.f / 192.f);
    float d0 = v0 - m, d1 = v1 - m, d2 = v2 - m;
    float qq = d0 * d0 + d1 * d1 + d2 * d2;
    for (int o = 32; o > 0; o >>= 1) qq += __shfl_down(qq, o);
    qq = __shfl(qq, 0);
    float inv = rsqrtf(qq * (1.f / 192.f) + 1e-5f);
    xl[t][lane]       = __float2bfloat16(d0 * inv * g[lane]       + bb[lane]);
    xl[t][lane + 64]  = __float2bfloat16(d1 * inv * g[lane + 64]  + bb[lane + 64]);
    xl[t][lane + 128] = __float2bfloat16(d2 * inv * g[lane + 128] + bb[lane + 128]);
  }
  __syncthreads();

  // A-frags for token-tiles 0,1 cached in regs; tiles 2,3 read from LDS per use
  short8 a1f[6][2];
#pragma unroll
  for (int kk = 0; kk < 6; ++kk) {
    a1f[kk][0] = lds8(&xl[colB][kk * 32 + 8 * grp]);
    a1f[kk][1] = lds8(&xl[16 + colB][kk * 32 + 8 * grp]);
  }

  float4v d[3][4];
#pragma unroll
  for (int j = 0; j < 3; ++j)
#pragma unroll
    for (int tt = 0; tt < 4; ++tt) d[j][tt] = (float4v){0, 0, 0, 0};
  int ntb = wave * 3;

  for (int ph = 0; ph < 2; ++ph) {
    if (ph) __syncthreads();  // prior fc2 reads of hh complete before overwrite
    for (int nn = 0; nn < 6; ++nn) {
      int ntl = wave * 6 + nn;
      int colg = ph * 384 + ntl * 16 + colB;
      short8 wf1[6];
#pragma unroll
      for (int kk = 0; kk < 6; ++kk)
        wf1[kk] = glb8(w1 + (size_t)colg * 192 + kk * 32 + 8 * grp);
      float4v c0 = {0,0,0,0}, c1 = {0,0,0,0}, c2 = {0,0,0,0}, c3 = {0,0,0,0};
#pragma unroll
      for (int kk = 0; kk < 6; ++kk) {
        c0 = __builtin_amdgcn_mfma_f32_16x16x32_bf16(a1f[kk][0], wf1[kk], c0, 0, 0, 0);
        c1 = __builtin_amdgcn_mfma_f32_16x16x32_bf16(a1f[kk][1], wf1[kk], c1, 0, 0, 0);
        c2 = __builtin_amdgcn_mfma_f32_16x16x32_bf16(lds8(&xl[32 + colB][kk * 32 + 8 * grp]), wf1[kk], c2, 0, 0, 0);
        c3 = __builtin_amdgcn_mfma_f32_16x16x32_bf16(lds8(&xl[48 + colB][kk * 32 + 8 * grp]), wf1[kk], c3, 0, 0, 0);
      }
      float bias = b1[colg];
      int coll = ntl * 16 + colB;
#pragma unroll
      for (int r = 0; r < 4; ++r) {
        float v0 = c0[r] + bias;
        float v1 = c1[r] + bias;
        float v2 = c2[r] + bias;
        float v3 = c3[r] + bias;
        v0 = v0 * 0.5f * (1.f + erff(v0 * 0.70710678118654752f));
        v1 = v1 * 0.5f * (1.f + erff(v1 * 0.70710678118654752f));
        v2 = v2 * 0.5f * (1.f + erff(v2 * 0.70710678118654752f));
        v3 = v3 * 0.5f * (1.f + erff(v3 * 0.70710678118654752f));
        hh[4 * grp + r][coll]      = __float2bfloat16(v0);
        hh[16 + 4 * grp + r][coll] = __float2bfloat16(v1);
        hh[32 + 4 * grp + r][coll] = __float2bfloat16(v2);
        hh[48 + 4 * grp + r][coll] = __float2bfloat16(v3);
      }
    }
    __syncthreads();
    for (int kk = 0; kk < 12; ++kk) {
      int kol = kk * 32 + 8 * grp;
      int kog = ph * 384 + kol;
      short8 wf2[3];
#pragma unroll
      for (int j = 0; j < 3; ++j)
        wf2[j] = glb8(w2 + (size_t)((ntb + j) * 16 + colB) * 768 + kog);
      short8 h0 = lds8(&hh[colB][kol]);
      short8 h1 = lds8(&hh[16 + colB][kol]);
      short8 h2 = lds8(&hh[32 + colB][kol]);
      short8 h3 = lds8(&hh[48 + colB][kol]);
#pragma unroll
      for (int j = 0; j < 3; ++j) {
        d[j][0] = __builtin_amdgcn_mfma_f32_16x16x32_bf16(h0, wf2[j], d[j][0], 0, 0, 0);
        d[j][1] = __builtin_amdgcn_mfma_f32_16x16x32_bf16(h1, wf2[j], d[j][1], 0, 0, 0);
        d[j][2] = __builtin_amdgcn_mfma_f32_16x16x32_bf16(h2, wf2[j], d[j][2], 0, 0, 0);
        d[j][3] = __builtin_amdgcn_mfma_f32_16x16x32_bf16(h3, wf2[j], d[j][3], 0, 0, 0);
      }
    }
  }

#pragma unroll
  for (int j = 0; j < 3; ++j) {
    int col = (ntb + j) * 16 + colB;
    float bias = b2[col];
#pragma unroll
    for (int tt = 0; tt < 4; ++tt) {
#pragma unroll
      for (int r = 0; r < 4; ++r) {
        size_t p = (tokbase + tt * 16 + 4 * grp + r) * 192 + col;
        x1[p] += d[j][tt][r] + bias;
      }
    }
  }
}

// ---------------- FUSED: SE gate + conv1x1 recompute + out += y*gate ----------------
__global__ __launch_bounds__(192) void k_final3(float* __restrict__ out, const float* __restrict__ t2,
                                                const float* __restrict__ c3w, const float* __restrict__ c3b,
                                                const float* __restrict__ s0, const float* __restrict__ w1se,
                                                const float* __restrict__ w2se) {
  __shared__ float mean[192];
  __shared__ float tt[24];
  __shared__ __align__(16) float t2l[64 * 24];
  int b = blockIdx.x >> 10;
  int chunk = blockIdx.x & 1023;
  int tid = threadIdx.x;  // 0..191
  mean[tid] = s0[b * 192 + tid] * (1.f / 65536.f);
  size_t pix0 = (size_t)b * 65536 + chunk * 64;
  for (int idx = tid; idx < 1536; idx += 192) t2l[idx] = t2[pix0 * 24 + idx];
  __syncthreads();
  if (tid < 24) {
    float a = 0.f;
    for (int c = 0; c < 192; ++c) a += mean[c] * w1se[tid * 192 + c];
    tt[tid] = fmaxf(a, 0.f);
  }
  __syncthreads();
  float a = 0.f;
#pragma unroll
  for (int r = 0; r < 24; ++r) a += tt[r] * w2se[tid * 24 + r];
  float gate = 1.f / (1.f + expf(-a));

  float wr3[24];
#pragma unroll
  for (int i = 0; i < 24; ++i) wr3[i] = c3w[tid * 24 + i];
  float b3 = c3b[tid];
  for (int p = 0; p < 64; ++p) {
    const float4v* rp = reinterpret_cast<const float4v*>(&t2l[p * 24]);
    float acc = b3;
#pragma unroll
    for (int v = 0; v < 6; ++v) {
      float4v q = rp[v];
      acc += q[0] * wr3[v * 4] + q[1] * wr3[v * 4 + 1] + q[2] * wr3[v * 4 + 2] + q[3] * wr3[v * 4 + 3];
    }
    if (acc < 0.f) acc *= 0.2f;
    out[(pix0 + p) * 192 + tid] += acc * gate;
  }
}

extern "C" void kernel_launch(void* const* d_in, const int* in_sizes, int n_in,
                              void* d_out, int out_size, void* d_ws, size_t ws_size,
                              hipStream_t stream) {
  const float* x     = (const float*)d_in[0];
  const float* n1g   = (const float*)d_in[1];
  const float* n1b   = (const float*)d_in[2];
  const float* qkvw  = (const float*)d_in[3];
  const float* qkvb  = (const float*)d_in[4];
  const float* rpb   = (const float*)d_in[5];
  const float* projw = (const float*)d_in[6];
  const float* projb = (const float*)d_in[7];
  const float* n2g   = (const float*)d_in[8];
  const float* n2b   = (const float*)d_in[9];
  const float* w1    = (const float*)d_in[10];
  const float* b1    = (const float*)d_in[11];
  const float* w2    = (const float*)d_in[12];
  const float* b2    = (const float*)d_in[13];
  const float* c1w   = (const float*)d_in[14];
  const float* c1b   = (const float*)d_in[15];
  const float* c2w   = (const float*)d_in[16];
  const float* c2b   = (const float*)d_in[17];
  const float* c3w   = (const float*)d_in[18];
  const float* c3b   = (const float*)d_in[19];
  const float* sfc1  = (const float*)d_in[20];
  const float* sfc2  = (const float*)d_in[21];
  float* out = (float*)d_out;

  if (ws_size < WS_NEEDED) return;

  char* ws = (char*)d_ws;
  float* t1   = (float*)(ws + OFF_T1);
  float* t2   = (float*)(ws + OFF_T2);
  float* s0   = (float*)(ws + OFF_S0);
  bf16*  wqkv = (bf16*)(ws + OFF_WQKV);
  bf16*  wprj = (bf16*)(ws + OFF_WPRJ);
  bf16*  wfc1 = (bf16*)(ws + OFF_WFC1);
  bf16*  wfc2 = (bf16*)(ws + OFF_WFC2);
  bf16*  c1wb = (bf16*)(ws + OFF_C1WB);

  hipFuncSetAttribute((const void*)k_mlp_lce2, hipFuncAttributeMaxDynamicSharedMemorySize, 75776);

  // weight converts + c1wb zero-pad + s0 zero, one dispatch
  k_f2b_all<<<1754, 256, 0, stream>>>(qkvw, projw, w1, w2, c1w,
                                      wqkv, wprj, wfc1, wfc2, c1wb, s0);

  // fused attention + LN1 + LCE conv1 (t1), writes x1 into d_out
  k_attn2<<<2048, 256, 0, stream>>>(x, n1g, n1b, wqkv, qkvb, rpb, wprj, projb,
                                    c1wb, c1b, t1, out);
  // FUSED: LCE conv3x3 + pool (blocks 0..511) | 64-token MLP (blocks 512..2559)
  k_mlp_lce2<<<2560, 256, 75776, stream>>>(out, n2g, n2b, wfc1, b1, wfc2, b2,
                                           t1, c2w, c2b, t2, c3w, c3b, s0);
  // FUSED: SE gate + conv1x1 recompute + out += y*gate
  k_final3<<<2048, 192, 0, stream>>>(out, t2, c3w, c3b, s0, sfc1, sfc2);
}

// Round 12
// 799.537 us; speedup vs baseline: 1.2356x; 1.1084x over previous
//
#include <hip/hip_runtime.h>
#include <hip/hip_bf16.h>

using bf16 = __hip_bfloat16;
typedef __attribute__((ext_vector_type(8))) short short8;
typedef __attribute__((ext_vector_type(4))) float float4v;

constexpr int NTOK = 131072;  // 2*256*256

// ---------------- workspace layout (bytes) ----------------
constexpr size_t OFF_T1   = 50331648;    // f32  [131072][24]     12,582,912
constexpr size_t OFF_T2   = 62914560;    // f32  [131072][24]     12,582,912
constexpr size_t OFF_S0   = 75497472;    // f32  [2][192]
constexpr size_t OFF_WQKV = 75500544;    // bf16 [576][192]       221,184
constexpr size_t OFF_WPRJ = 75721728;    // bf16 [192][192]        73,728
constexpr size_t OFF_WFC1 = 75795456;    // bf16 [768][192]       294,912
constexpr size_t OFF_WFC2 = 76090368;    // bf16 [192][768]       294,912
constexpr size_t OFF_C1WB = 76385280;    // bf16 [32][192]         12,288 (rows 24..31 zero)
constexpr size_t WS_NEEDED = 76397568;

__device__ __forceinline__ int region256(int t) { return t < 248 ? 0 : (t < 252 ? 1 : 2); }

__device__ __forceinline__ short8 lds8(const bf16* p) {
  return *reinterpret_cast<const short8*>(p);
}
__device__ __forceinline__ short8 glb8(const bf16* p) {
  return *reinterpret_cast<const short8*>(p);
}

// ---------------- fp32 -> bf16 weight convert + zero-init (one dispatch) ----------------
__global__ __launch_bounds__(256) void k_f2b_all(const float* __restrict__ qkvw, const float* __restrict__ projw,
                                                 const float* __restrict__ w1, const float* __restrict__ w2,
                                                 const float* __restrict__ c1w,
                                                 bf16* __restrict__ wqkv, bf16* __restrict__ wprj,
                                                 bf16* __restrict__ wfc1, bf16* __restrict__ wfc2,
                                                 bf16* __restrict__ c1wb, float* __restrict__ s0) {
  int i = blockIdx.x * 256 + threadIdx.x;
  if (i < 110592) { wqkv[i] = __float2bfloat16(qkvw[i]); return; }
  i -= 110592;
  if (i < 36864) { wprj[i] = __float2bfloat16(projw[i]); return; }
  i -= 36864;
  if (i < 147456) { wfc1[i] = __float2bfloat16(w1[i]); return; }
  i -= 147456;
  if (i < 147456) { wfc2[i] = __float2bfloat16(w2[i]); return; }
  i -= 147456;
  if (i < 4608) { c1wb[i] = __float2bfloat16(c1w[i]); return; }
  i -= 4608;
  if (i < 1536) { c1wb[4608 + i] = __float2bfloat16(0.f); return; }  // pad rows 24..31
  i -= 1536;
  if (i < 384) s0[i] = 0.f;
}

// ---------------- 2-window fused attention (+ LCE conv1) ----------------
// R12: each block handles 2 adjacent windows (128 tokens). Every weight
// fragment (QKV wf[6], proj wfp[9], conv1) now feeds BOTH windows' A-frags
// -> weight-load latency per token halves (the lever that won twice on the
// MLP). 1024 blocks at 2/CU = exactly 2 full scheduling rounds (was 2048 at
// 3/CU = 2.67 rounds, ~11% tail waste). LDS 73,728 B dynamic -> 2 blocks/CU.
// (256,2) cap 256 regs: wf[6] batches + doubled axw fit with no spill.
// Regions (same (r&7)<<4 XOR swizzle; write/read use identical mapping):
//   STG @0      [128][192] bf16 stride 384 (LN rows then O; rows 0-63 winA, 64-127 winB)
//   KL1 @49152  [128 tok][32 ch] bf16 stride 64
//   VT1 @57344  [32 ch][128 tok] bf16 stride 256
//   PS3 @65536  [64][64]  bf16 stride 128 (per-wave Q/P scratch, time-shared A->B)
__device__ __forceinline__ int stg_b(int r, int c) { return (r * 384 + c * 2) ^ ((r & 7) << 4); }
__device__ __forceinline__ int kl1_b(int r, int c) { return 49152 + ((r * 64 + c * 2) ^ ((r & 7) << 4)); }
__device__ __forceinline__ int vt1_b(int r, int c) { return 57344 + ((r * 256 + c * 2) ^ ((r & 7) << 4)); }
__device__ __forceinline__ int ps3_b(int r, int c) { return 65536 + ((r * 128 + c * 2) ^ ((r & 7) << 4)); }

__device__ __forceinline__ short8 lds8o(const char* sm, int byteoff) {
  return *reinterpret_cast<const short8*>(sm + byteoff);
}
__device__ __forceinline__ void st16(char* sm, int byteoff, bf16 v) {
  *reinterpret_cast<bf16*>(sm + byteoff) = v;
}

constexpr int SMEM_ATTN = 73728;

__global__ __launch_bounds__(256, 2) void k_attn2(const float* __restrict__ x, const float* __restrict__ g,
                                                  const float* __restrict__ bb, const bf16* __restrict__ wq,
                                                  const float* __restrict__ qkvb, const float* __restrict__ rpb,
                                                  const bf16* __restrict__ wp, const float* __restrict__ projb,
                                                  const bf16* __restrict__ c1wb, const float* __restrict__ c1b,
                                                  float* __restrict__ t1, float* __restrict__ x1out) {
  extern __shared__ char sm[];

  int pb = blockIdx.x;            // 1024 = 2 * 32 * 16
  int b = pb >> 9;
  int rem = pb & 511;
  int wh = rem >> 4, pw = rem & 15;
  int ww0 = pw << 1;              // windows ww0 and ww0+1
  int tid = threadIdx.x;
  int wave = tid >> 6, lane = tid & 63;
  int colB = lane & 15, grp = lane >> 4;
  const float scale = 0.17677669529663687f;  // 1/sqrt(32)

  // ---- Phase 1: LN over this wave's 16 tokens x 2 windows -> staging (wave-private rows)
#pragma unroll
  for (int wn = 0; wn < 2; ++wn) {
    int wwc = ww0 + wn;
    for (int t = 0; t < 16; ++t) {
      int tok = wave * 16 + t;
      int i = tok >> 3, j = tok & 7;
      int hp = (wh * 8 + i + 4) & 255;
      int wpp = (wwc * 8 + j + 4) & 255;
      const float* xr = x + (((size_t)b << 16) + (hp << 8) + wpp) * 192;
      float v0 = xr[lane], v1 = xr[lane + 64], v2 = xr[lane + 128];
      float s = v0 + v1 + v2;
      for (int o = 32; o > 0; o >>= 1) s += __shfl_down(s, o);
      s = __shfl(s, 0);
      float m = s * (1.f / 192.f);
      float d0 = v0 - m, d1 = v1 - m, d2 = v2 - m;
      float q = d0 * d0 + d1 * d1 + d2 * d2;
      for (int o = 32; o > 0; o >>= 1) q += __shfl_down(q, o);
      q = __shfl(q, 0);
      float inv = rsqrtf(q * (1.f / 192.f) + 1e-5f);
      int sr = wn * 64 + tok;
      st16(sm, stg_b(sr, lane),       __float2bfloat16(d0 * inv * g[lane]       + bb[lane]));
      st16(sm, stg_b(sr, lane + 64),  __float2bfloat16(d1 * inv * g[lane + 64]  + bb[lane + 64]));
      st16(sm, stg_b(sr, lane + 128), __float2bfloat16(d2 * inv * g[lane + 128] + bb[lane + 128]));
    }
  }

  short8 axwA[6], axwB[6];
#pragma unroll
  for (int kk = 0; kk < 6; ++kk) {
    axwA[kk] = lds8o(sm, stg_b(wave * 16 + colB, kk * 32 + 8 * grp));
    axwB[kk] = lds8o(sm, stg_b(64 + wave * 16 + colB, kk * 32 + 8 * grp));
  }

  int i1r[4], j1r[4], l1rA[4], l1rB[4];
#pragma unroll
  for (int r = 0; r < 4; ++r) {
    int n = wave * 16 + 4 * grp + r;
    i1r[r] = n >> 3; j1r[r] = n & 7;
    int rh = region256(wh * 8 + i1r[r]) * 3;
    l1rA[r] = rh + region256(ww0 * 8 + j1r[r]);
    l1rB[r] = rh + region256((ww0 + 1) * 8 + j1r[r]);
  }

  for (int gch = 0; gch < 6; ++gch) {  // chunk = head gch = qkv cols 32g..32g+31
    float qreg[16];  // [win*8 + jt*4 + r]
    {  // Q: 6-frag batches shared by both windows
      float4v qa[4] = {{0,0,0,0},{0,0,0,0},{0,0,0,0},{0,0,0,0}};
      short8 wf[6];
#pragma unroll
      for (int h2 = 0; h2 < 2; ++h2) {
#pragma unroll
        for (int kk = 0; kk < 3; ++kk)
#pragma unroll
          for (int jt = 0; jt < 2; ++jt)
            wf[kk * 2 + jt] = glb8(wq + (size_t)(gch * 32 + jt * 16 + colB) * 192 + (h2 * 3 + kk) * 32 + 8 * grp);
#pragma unroll
        for (int kk = 0; kk < 3; ++kk)
#pragma unroll
          for (int jt = 0; jt < 2; ++jt) {
            qa[jt]     = __builtin_amdgcn_mfma_f32_16x16x32_bf16(axwA[h2 * 3 + kk], wf[kk * 2 + jt], qa[jt], 0, 0, 0);
            qa[2 + jt] = __builtin_amdgcn_mfma_f32_16x16x32_bf16(axwB[h2 * 3 + kk], wf[kk * 2 + jt], qa[2 + jt], 0, 0, 0);
          }
      }
#pragma unroll
      for (int jt = 0; jt < 2; ++jt) {
        float bias = qkvb[gch * 32 + jt * 16 + colB];
#pragma unroll
        for (int r = 0; r < 4; ++r) {
          qreg[jt * 4 + r]     = (qa[jt][r] + bias) * scale;
          qreg[8 + jt * 4 + r] = (qa[2 + jt][r] + bias) * scale;
        }
      }
    }
    {  // K -> KL1 (rows: winA 0-63, winB 64-127)
      float4v ka[4] = {{0,0,0,0},{0,0,0,0},{0,0,0,0},{0,0,0,0}};
      short8 wf[6];
#pragma unroll
      for (int h2 = 0; h2 < 2; ++h2) {
#pragma unroll
        for (int kk = 0; kk < 3; ++kk)
#pragma unroll
          for (int jt = 0; jt < 2; ++jt)
            wf[kk * 2 + jt] = glb8(wq + (size_t)(192 + gch * 32 + jt * 16 + colB) * 192 + (h2 * 3 + kk) * 32 + 8 * grp);
#pragma unroll
        for (int kk = 0; kk < 3; ++kk)
#pragma unroll
          for (int jt = 0; jt < 2; ++jt) {
            ka[jt]     = __builtin_amdgcn_mfma_f32_16x16x32_bf16(axwA[h2 * 3 + kk], wf[kk * 2 + jt], ka[jt], 0, 0, 0);
            ka[2 + jt] = __builtin_amdgcn_mfma_f32_16x16x32_bf16(axwB[h2 * 3 + kk], wf[kk * 2 + jt], ka[2 + jt], 0, 0, 0);
          }
      }
#pragma unroll
      for (int jt = 0; jt < 2; ++jt) {
        float bias = qkvb[192 + gch * 32 + jt * 16 + colB];
#pragma unroll
        for (int r = 0; r < 4; ++r) {
          st16(sm, kl1_b(wave * 16 + 4 * grp + r, jt * 16 + colB), __float2bfloat16(ka[jt][r] + bias));
          st16(sm, kl1_b(64 + wave * 16 + 4 * grp + r, jt * 16 + colB), __float2bfloat16(ka[2 + jt][r] + bias));
        }
      }
    }
    {  // V -> VT1 (transposed; cols: winA 0-63, winB 64-127)
      float4v va[4] = {{0,0,0,0},{0,0,0,0},{0,0,0,0},{0,0,0,0}};
      short8 wf[6];
#pragma unroll
      for (int h2 = 0; h2 < 2; ++h2) {
#pragma unroll
        for (int kk = 0; kk < 3; ++kk)
#pragma unroll
          for (int jt = 0; jt < 2; ++jt)
            wf[kk * 2 + jt] = glb8(wq + (size_t)(384 + gch * 32 + jt * 16 + colB) * 192 + (h2 * 3 + kk) * 32 + 8 * grp);
#pragma unroll
        for (int kk = 0; kk < 3; ++kk)
#pragma unroll
          for (int jt = 0; jt < 2; ++jt) {
            va[jt]     = __builtin_amdgcn_mfma_f32_16x16x32_bf16(axwA[h2 * 3 + kk], wf[kk * 2 + jt], va[jt], 0, 0, 0);
            va[2 + jt] = __builtin_amdgcn_mfma_f32_16x16x32_bf16(axwB[h2 * 3 + kk], wf[kk * 2 + jt], va[2 + jt], 0, 0, 0);
          }
      }
#pragma unroll
      for (int jt = 0; jt < 2; ++jt) {
        float bias = qkvb[384 + gch * 32 + jt * 16 + colB];
#pragma unroll
        for (int r = 0; r < 4; ++r) {
          st16(sm, vt1_b(jt * 16 + colB, wave * 16 + 4 * grp + r), __float2bfloat16(va[jt][r] + bias));
          st16(sm, vt1_b(jt * 16 + colB, 64 + wave * 16 + 4 * grp + r), __float2bfloat16(va[2 + jt][r] + bias));
        }
      }
    }
    if (gch == 0) {  // conv1 (LCE): shared weight batches, both windows
      float4v accA[2] = {{0,0,0,0},{0,0,0,0}};
      float4v accB[2] = {{0,0,0,0},{0,0,0,0}};
      short8 wf[6];
#pragma unroll
      for (int h2 = 0; h2 < 2; ++h2) {
#pragma unroll
        for (int kk = 0; kk < 3; ++kk)
#pragma unroll
          for (int j = 0; j < 2; ++j)
            wf[kk * 2 + j] = glb8(c1wb + (size_t)(j * 16 + colB) * 192 + (h2 * 3 + kk) * 32 + 8 * grp);
#pragma unroll
        for (int kk = 0; kk < 3; ++kk)
#pragma unroll
          for (int j = 0; j < 2; ++j) {
            accA[j] = __builtin_amdgcn_mfma_f32_16x16x32_bf16(axwA[h2 * 3 + kk], wf[kk * 2 + j], accA[j], 0, 0, 0);
            accB[j] = __builtin_amdgcn_mfma_f32_16x16x32_bf16(axwB[h2 * 3 + kk], wf[kk * 2 + j], accB[j], 0, 0, 0);
          }
      }
#pragma unroll
      for (int j = 0; j < 2; ++j) {
        int ch = j * 16 + colB;
        if (ch < 24) {
          float bias = c1b[ch];
#pragma unroll
          for (int r = 0; r < 4; ++r) {
            int tok = wave * 16 + 4 * grp + r;
            int i = tok >> 3, jj = tok & 7;
            int hp = (wh * 8 + i + 4) & 255;
            int wppA = (ww0 * 8 + jj + 4) & 255;
            int wppB = ((ww0 + 1) * 8 + jj + 4) & 255;
            t1[(((size_t)b << 16) + (hp << 8) + wppA) * 24 + ch] = accA[j][r] + bias;
            t1[(((size_t)b << 16) + (hp << 8) + wppB) * 24 + ch] = accB[j][r] + bias;
          }
        }
      }
    }
    __syncthreads();  // K/V of this chunk visible to all waves

    // ---- attention for head h = gch, window A then window B (PS3 time-shared)
#pragma unroll
    for (int wn = 0; wn < 2; ++wn) {
      int h = gch;
      int wwc = ww0 + wn;
#pragma unroll
      for (int t = 0; t < 2; ++t)
#pragma unroll
        for (int r = 0; r < 4; ++r)
          st16(sm, ps3_b(wave * 16 + 4 * grp + r, t * 16 + colB), __float2bfloat16(qreg[wn * 8 + t * 4 + r]));
      short8 aq = lds8o(sm, ps3_b(wave * 16 + colB, 8 * grp));

      float4v s[4];
#pragma unroll
      for (int nt = 0; nt < 4; ++nt) {
        short8 bk = lds8o(sm, kl1_b(wn * 64 + nt * 16 + colB, 8 * grp));
        float4v z = {0, 0, 0, 0};
        s[nt] = __builtin_amdgcn_mfma_f32_16x16x32_bf16(aq, bk, z, 0, 0, 0);
      }
#pragma unroll
      for (int nt = 0; nt < 4; ++nt) {
        int m = nt * 16 + colB;
        int i2 = m >> 3, j2 = m & 7;
        int l2 = region256(wh * 8 + i2) * 3 + region256(wwc * 8 + j2);
#pragma unroll
        for (int r = 0; r < 4; ++r) {
          int l1 = wn ? l1rB[r] : l1rA[r];
          float bias = rpb[((i1r[r] - i2 + 7) * 15 + (j1r[r] - j2 + 7)) * 6 + h];
          s[nt][r] += bias + (l1 != l2 ? -100.f : 0.f);
        }
      }
#pragma unroll
      for (int r = 0; r < 4; ++r) {
        float mx = fmaxf(fmaxf(s[0][r], s[1][r]), fmaxf(s[2][r], s[3][r]));
        mx = fmaxf(mx, __shfl_xor(mx, 1));
        mx = fmaxf(mx, __shfl_xor(mx, 2));
        mx = fmaxf(mx, __shfl_xor(mx, 4));
        mx = fmaxf(mx, __shfl_xor(mx, 8));
        float e0 = __expf(s[0][r] - mx), e1 = __expf(s[1][r] - mx);
        float e2 = __expf(s[2][r] - mx), e3 = __expf(s[3][r] - mx);
        float sum = e0 + e1 + e2 + e3;
        sum += __shfl_xor(sum, 1);
        sum += __shfl_xor(sum, 2);
        sum += __shfl_xor(sum, 4);
        sum += __shfl_xor(sum, 8);
        float inv = 1.f / sum;
        int row = wave * 16 + 4 * grp + r;
        st16(sm, ps3_b(row, 0 * 16 + colB), __float2bfloat16(e0 * inv));
        st16(sm, ps3_b(row, 1 * 16 + colB), __float2bfloat16(e1 * inv));
        st16(sm, ps3_b(row, 2 * 16 + colB), __float2bfloat16(e2 * inv));
        st16(sm, ps3_b(row, 3 * 16 + colB), __float2bfloat16(e3 * inv));
      }
      short8 ap0 = lds8o(sm, ps3_b(wave * 16 + colB, 8 * grp));
      short8 ap1 = lds8o(sm, ps3_b(wave * 16 + colB, 32 + 8 * grp));

      float4v o0 = {0, 0, 0, 0}, o1 = {0, 0, 0, 0};
      o0 = __builtin_amdgcn_mfma_f32_16x16x32_bf16(ap0, lds8o(sm, vt1_b(colB, wn * 64 + 8 * grp)), o0, 0, 0, 0);
      o0 = __builtin_amdgcn_mfma_f32_16x16x32_bf16(ap1, lds8o(sm, vt1_b(colB, wn * 64 + 32 + 8 * grp)), o0, 0, 0, 0);
      o1 = __builtin_amdgcn_mfma_f32_16x16x32_bf16(ap0, lds8o(sm, vt1_b(16 + colB, wn * 64 + 8 * grp)), o1, 0, 0, 0);
      o1 = __builtin_amdgcn_mfma_f32_16x16x32_bf16(ap1, lds8o(sm, vt1_b(16 + colB, wn * 64 + 32 + 8 * grp)), o1, 0, 0, 0);
      int ocol = gch * 32;
#pragma unroll
      for (int r = 0; r < 4; ++r) {
        int row = wn * 64 + wave * 16 + 4 * grp + r;
        st16(sm, stg_b(row, ocol + colB),      __float2bfloat16(o0[r]));
        st16(sm, stg_b(row, ocol + 16 + colB), __float2bfloat16(o1[r]));
      }
    }
    if (gch != 5) __syncthreads();
  }

  // ---- Phase 4: proj (shared wfp batches for both windows) + scatter + residual
  short8 aoA[6], aoB[6];
#pragma unroll
  for (int kk = 0; kk < 6; ++kk) {
    aoA[kk] = lds8o(sm, stg_b(wave * 16 + colB, kk * 32 + 8 * grp));
    aoB[kk] = lds8o(sm, stg_b(64 + wave * 16 + colB, kk * 32 + 8 * grp));
  }
  for (int gp = 0; gp < 4; ++gp) {
    float4v accA[3] = {{0,0,0,0},{0,0,0,0},{0,0,0,0}};
    float4v accB[3] = {{0,0,0,0},{0,0,0,0},{0,0,0,0}};
#pragma unroll
    for (int half = 0; half < 2; ++half) {
      short8 wfp[9];
#pragma unroll
      for (int kk = 0; kk < 3; ++kk)
#pragma unroll
        for (int j = 0; j < 3; ++j)
          wfp[kk * 3 + j] = glb8(wp + (size_t)((gp * 3 + j) * 16 + colB) * 192 + (half * 3 + kk) * 32 + 8 * grp);
#pragma unroll
      for (int kk = 0; kk < 3; ++kk)
#pragma unroll
        for (int j = 0; j < 3; ++j) {
          accA[j] = __builtin_amdgcn_mfma_f32_16x16x32_bf16(aoA[half * 3 + kk], wfp[kk * 3 + j], accA[j], 0, 0, 0);
          accB[j] = __builtin_amdgcn_mfma_f32_16x16x32_bf16(aoB[half * 3 + kk], wfp[kk * 3 + j], accB[j], 0, 0, 0);
        }
    }
#pragma unroll
    for (int j = 0; j < 3; ++j) {
      int col = (gp * 3 + j) * 16 + colB;
      float bias = projb[col];
#pragma unroll
      for (int r = 0; r < 4; ++r) {
        int n = wave * 16 + 4 * grp + r;
        int i = n >> 3, jj = n & 7;
        int hd2 = (wh * 8 + i + 4) & 255;
        int wdA = (ww0 * 8 + jj + 4) & 255;
        int wdB = ((ww0 + 1) * 8 + jj + 4) & 255;
        size_t pA = (((size_t)b << 16) + (hd2 << 8) + wdA) * 192 + col;
        size_t pB = (((size_t)b << 16) + (hd2 << 8) + wdB) * 192 + col;
        x1out[pA] = x[pA] + accA[j][r] + bias;
        x1out[pB] = x[pB] + accB[j][r] + bias;
      }
    }
  }
}

// ---------------- FUSED: [LCE conv3x3 + conv1x1-pool (512 blocks)] | [MFMA MLP 64-tok (2048 blocks)] ----------------
// R9 config (best measured): 64-token MLP, reuse-4 per weight fragment,
// fc1/fc2 batch-loads, hh full 768 cols [64][392], 2 blocks/CU.
__global__ __launch_bounds__(256, 2) void k_mlp_lce2(float* __restrict__ x1, const float* __restrict__ g,
                                                     const float* __restrict__ bb, const bf16* __restrict__ w1,
                                                     const float* __restrict__ b1, const bf16* __restrict__ w2,
                                                     const float* __restrict__ b2,
                                                     const float* __restrict__ t1, const float* __restrict__ cw,
                                                     const float* __restrict__ cbia, float* __restrict__ t2,
                                                     const float* __restrict__ c3w, const float* __restrict__ c3b,
                                                     float* __restrict__ s0) {
  extern __shared__ __align__(16) char smu[];
  int tid = threadIdx.x;

  if (blockIdx.x < 512) {
    // ---------- LCE conv3x3 24->24 ----------
    float* halo = (float*)smu;            // 18*18*25 floats = 32,400 B
    float* wlds = (float*)(smu + 32400);  // 5184 floats = 20,736 B
    int bid = blockIdx.x;
    int b = bid >> 8;
    int rem = bid & 255;
    int ty0 = ((rem >> 4) & 15) * 16, tx0 = (rem & 15) * 16;
    for (int idx = tid; idx < 5184; idx += 256) wlds[idx] = cw[idx];
    for (int idx = tid; idx < 18 * 18 * 24; idx += 256) {
      int ch = idx % 24;
      int pp = idx / 24;
      int hy = pp / 18, hx = pp - hy * 18;
      int gy = ty0 + hy - 1, gx = tx0 + hx - 1;
      float v = 0.f;
      if (gy >= 0 && gy < 256 && gx >= 0 && gx < 256)
        v = t1[((size_t)(b << 16) + (gy << 8) + gx) * 24 + ch];
      halo[pp * 25 + ch] = v;
    }
    __syncthreads();
    int py = tid >> 4, px = tid & 15;
    float acc[24];
#pragma unroll
    for (int ro = 0; ro < 24; ++ro) acc[ro] = cbia[ro];
    for (int ky = 0; ky < 3; ++ky) {
      for (int kx = 0; kx < 3; ++kx) {
        int base = ((py + ky) * 18 + px + kx) * 25;
        float inb[24];
#pragma unroll
        for (int ri = 0; ri < 24; ++ri) inb[ri] = halo[base + ri];
        int wo = ky * 3 + kx;
#pragma unroll
        for (int ro = 0; ro < 24; ++ro) {
          float a = acc[ro];
#pragma unroll
          for (int ri = 0; ri < 24; ++ri) a += inb[ri] * wlds[ro * 216 + ri * 9 + wo];
          acc[ro] = a;
        }
      }
    }
    size_t pix = (size_t)(b << 16) + ((ty0 + py) << 8) + tx0 + px;
#pragma unroll
    for (int ro = 0; ro < 24; ++ro) t2[pix * 24 + ro] = acc[ro];

    // ---------- conv1x1 24->192 + LeakyReLU pool partials ----------
    __syncthreads();
    float* t2l = (float*)smu;            // [256][28] floats = 28,672 B
#pragma unroll
    for (int ro = 0; ro < 24; ++ro) t2l[tid * 28 + ro] = acc[ro];
    __syncthreads();
    if (tid < 192) {
      float wr3[24];
#pragma unroll
      for (int i2 = 0; i2 < 24; ++i2) wr3[i2] = c3w[tid * 24 + i2];
      float b3 = c3b[tid];
      float ps = 0.f;
      for (int p = 0; p < 256; ++p) {
        const float4v* rp = reinterpret_cast<const float4v*>(&t2l[p * 28]);
        float a = b3;
#pragma unroll
        for (int v = 0; v < 6; ++v) {
          float4v q = rp[v];
          a += q[0] * wr3[v * 4] + q[1] * wr3[v * 4 + 1] + q[2] * wr3[v * 4 + 2] + q[3] * wr3[v * 4 + 3];
        }
        ps += (a < 0.f) ? 0.2f * a : a;
      }
      atomicAdd(&s0[b * 192 + tid], ps);
    }
    return;
  }

  // ---------- MFMA MLP: 64 tokens, LN2 + fc1 + GELU + fc2 + residual ----------
  // xl @0: [64][200] bf16 (25,600 B); hh @25600: [64][392] bf16 (50,176 B)
  bf16 (*xl)[200] = reinterpret_cast<bf16(*)[200]>(smu);
  bf16 (*hh)[392] = reinterpret_cast<bf16(*)[392]>(smu + 25600);
  int wave = tid >> 6, lane = tid & 63;
  int colB = lane & 15, grp = lane >> 4;
  size_t tokbase = (size_t)(blockIdx.x - 512) * 64;

  for (int t = wave; t < 64; t += 4) {
    const float* xr = x1 + (tokbase + t) * 192;
    float v0 = xr[lane], v1 = xr[lane + 64], v2 = xr[lane + 128];
    float s = v0 + v1 + v2;
    for (int o = 32; o > 0; o >>= 1) s += __shfl_down(s, o);
    s = __shfl(s, 0);
    float m = s * (1.f / 192.f);
    float d0 = v0 - m, d1 = v1 - m, d2 = v2 - m;
    float qq = d0 * d0 + d1 * d1 + d2 * d2;
    for (int o = 32; o > 0; o >>= 1) qq += __shfl_down(qq, o);
    qq = __shfl(qq, 0);
    float inv = rsqrtf(qq * (1.f / 192.f) + 1e-5f);
    xl[t][lane]       = __float2bfloat16(d0 * inv * g[lane]       + bb[lane]);
    xl[t][lane + 64]  = __float2bfloat16(d1 * inv * g[lane + 64]  + bb[lane + 64]);
    xl[t][lane + 128] = __float2bfloat16(d2 * inv * g[lane + 128] + bb[lane + 128]);
  }
  __syncthreads();

  // A-frags for token-tiles 0,1 cached in regs; tiles 2,3 read from LDS per use
  short8 a1f[6][2];
#pragma unroll
  for (int kk = 0; kk < 6; ++kk) {
    a1f[kk][0] = lds8(&xl[colB][kk * 32 + 8 * grp]);
    a1f[kk][1] = lds8(&xl[16 + colB][kk * 32 + 8 * grp]);
  }

  float4v d[3][4];
#pragma unroll
  for (int j = 0; j < 3; ++j)
#pragma unroll
    for (int tt = 0; tt < 4; ++tt) d[j][tt] = (float4v){0, 0, 0, 0};
  int ntb = wave * 3;

  for (int ph = 0; ph < 2; ++ph) {
    if (ph) __syncthreads();  // prior fc2 reads of hh complete before overwrite
    for (int nn = 0; nn < 6; ++nn) {
      int ntl = wave * 6 + nn;
      int colg = ph * 384 + ntl * 16 + colB;
      short8 wf1[6];
#pragma unroll
      for (int kk = 0; kk < 6; ++kk)
        wf1[kk] = glb8(w1 + (size_t)colg * 192 + kk * 32 + 8 * grp);
      float4v c0 = {0,0,0,0}, c1 = {0,0,0,0}, c2 = {0,0,0,0}, c3 = {0,0,0,0};
#pragma unroll
      for (int kk = 0; kk < 6; ++kk) {
        c0 = __builtin_amdgcn_mfma_f32_16x16x32_bf16(a1f[kk][0], wf1[kk], c0, 0, 0, 0);
        c1 = __builtin_amdgcn_mfma_f32_16x16x32_bf16(a1f[kk][1], wf1[kk], c1, 0, 0, 0);
        c2 = __builtin_amdgcn_mfma_f32_16x16x32_bf16(lds8(&xl[32 + colB][kk * 32 + 8 * grp]), wf1[kk], c2, 0, 0, 0);
        c3 = __builtin_amdgcn_mfma_f32_16x16x32_bf16(lds8(&xl[48 + colB][kk * 32 + 8 * grp]), wf1[kk], c3, 0, 0, 0);
      }
      float bias = b1[colg];
      int coll = ntl * 16 + colB;
#pragma unroll
      for (int r = 0; r < 4; ++r) {
        float v0 = c0[r] + bias;
        float v1 = c1[r] + bias;
        float v2 = c2[r] + bias;
        float v3 = c3[r] + bias;
        v0 = v0 * 0.5f * (1.f + erff(v0 * 0.70710678118654752f));
        v1 = v1 * 0.5f * (1.f + erff(v1 * 0.70710678118654752f));
        v2 = v2 * 0.5f * (1.f + erff(v2 * 0.70710678118654752f));
        v3 = v3 * 0.5f * (1.f + erff(v3 * 0.70710678118654752f));
        hh[4 * grp + r][coll]      = __float2bfloat16(v0);
        hh[16 + 4 * grp + r][coll] = __float2bfloat16(v1);
        hh[32 + 4 * grp + r][coll] = __float2bfloat16(v2);
        hh[48 + 4 * grp + r][coll] = __float2bfloat16(v3);
      }
    }
    __syncthreads();
    for (int kk = 0; kk < 12; ++kk) {
      int kol = kk * 32 + 8 * grp;
      int kog = ph * 384 + kol;
      short8 wf2[3];
#pragma unroll
      for (int j = 0; j < 3; ++j)
        wf2[j] = glb8(w2 + (size_t)((ntb + j) * 16 + colB) * 768 + kog);
      short8 h0 = lds8(&hh[colB][kol]);
      short8 h1 = lds8(&hh[16 + colB][kol]);
      short8 h2 = lds8(&hh[32 + colB][kol]);
      short8 h3 = lds8(&hh[48 + colB][kol]);
#pragma unroll
      for (int j = 0; j < 3; ++j) {
        d[j][0] = __builtin_amdgcn_mfma_f32_16x16x32_bf16(h0, wf2[j], d[j][0], 0, 0, 0);
        d[j][1] = __builtin_amdgcn_mfma_f32_16x16x32_bf16(h1, wf2[j], d[j][1], 0, 0, 0);
        d[j][2] = __builtin_amdgcn_mfma_f32_16x16x32_bf16(h2, wf2[j], d[j][2], 0, 0, 0);
        d[j][3] = __builtin_amdgcn_mfma_f32_16x16x32_bf16(h3, wf2[j], d[j][3], 0, 0, 0);
      }
    }
  }

#pragma unroll
  for (int j = 0; j < 3; ++j) {
    int col = (ntb + j) * 16 + colB;
    float bias = b2[col];
#pragma unroll
    for (int tt = 0; tt < 4; ++tt) {
#pragma unroll
      for (int r = 0; r < 4; ++r) {
        size_t p = (tokbase + tt * 16 + 4 * grp + r) * 192 + col;
        x1[p] += d[j][tt][r] + bias;
      }
    }
  }
}

// ---------------- FUSED: SE gate + conv1x1 recompute + out += y*gate ----------------
__global__ __launch_bounds__(192) void k_final3(float* __restrict__ out, const float* __restrict__ t2,
                                                const float* __restrict__ c3w, const float* __restrict__ c3b,
                                                const float* __restrict__ s0, const float* __restrict__ w1se,
                                                const float* __restrict__ w2se) {
  __shared__ float mean[192];
  __shared__ float tt[24];
  __shared__ __align__(16) float t2l[64 * 24];
  int b = blockIdx.x >> 10;
  int chunk = blockIdx.x & 1023;
  int tid = threadIdx.x;  // 0..191
  mean[tid] = s0[b * 192 + tid] * (1.f / 65536.f);
  size_t pix0 = (size_t)b * 65536 + chunk * 64;
  for (int idx = tid; idx < 1536; idx += 192) t2l[idx] = t2[pix0 * 24 + idx];
  __syncthreads();
  if (tid < 24) {
    float a = 0.f;
    for (int c = 0; c < 192; ++c) a += mean[c] * w1se[tid * 192 + c];
    tt[tid] = fmaxf(a, 0.f);
  }
  __syncthreads();
  float a = 0.f;
#pragma unroll
  for (int r = 0; r < 24; ++r) a += tt[r] * w2se[tid * 24 + r];
  float gate = 1.f / (1.f + expf(-a));

  float wr3[24];
#pragma unroll
  for (int i = 0; i < 24; ++i) wr3[i] = c3w[tid * 24 + i];
  float b3 = c3b[tid];
  for (int p = 0; p < 64; ++p) {
    const float4v* rp = reinterpret_cast<const float4v*>(&t2l[p * 24]);
    float acc = b3;
#pragma unroll
    for (int v = 0; v < 6; ++v) {
      float4v q = rp[v];
      acc += q[0] * wr3[v * 4] + q[1] * wr3[v * 4 + 1] + q[2] * wr3[v * 4 + 2] + q[3] * wr3[v * 4 + 3];
    }
    if (acc < 0.f) acc *= 0.2f;
    out[(pix0 + p) * 192 + tid] += acc * gate;
  }
}

extern "C" void kernel_launch(void* const* d_in, const int* in_sizes, int n_in,
                              void* d_out, int out_size, void* d_ws, size_t ws_size,
                              hipStream_t stream) {
  const float* x     = (const float*)d_in[0];
  const float* n1g   = (const float*)d_in[1];
  const float* n1b   = (const float*)d_in[2];
  const float* qkvw  = (const float*)d_in[3];
  const float* qkvb  = (const float*)d_in[4];
  const float* rpb   = (const float*)d_in[5];
  const float* projw = (const float*)d_in[6];
  const float* projb = (const float*)d_in[7];
  const float* n2g   = (const float*)d_in[8];
  const float* n2b   = (const float*)d_in[9];
  const float* w1    = (const float*)d_in[10];
  const float* b1    = (const float*)d_in[11];
  const float* w2    = (const float*)d_in[12];
  const float* b2    = (const float*)d_in[13];
  const float* c1w   = (const float*)d_in[14];
  const float* c1b   = (const float*)d_in[15];
  const float* c2w   = (const float*)d_in[16];
  const float* c2b   = (const float*)d_in[17];
  const float* c3w   = (const float*)d_in[18];
  const float* c3b   = (const float*)d_in[19];
  const float* sfc1  = (const float*)d_in[20];
  const float* sfc2  = (const float*)d_in[21];
  float* out = (float*)d_out;

  if (ws_size < WS_NEEDED) return;

  char* ws = (char*)d_ws;
  float* t1   = (float*)(ws + OFF_T1);
  float* t2   = (float*)(ws + OFF_T2);
  float* s0   = (float*)(ws + OFF_S0);
  bf16*  wqkv = (bf16*)(ws + OFF_WQKV);
  bf16*  wprj = (bf16*)(ws + OFF_WPRJ);
  bf16*  wfc1 = (bf16*)(ws + OFF_WFC1);
  bf16*  wfc2 = (bf16*)(ws + OFF_WFC2);
  bf16*  c1wb = (bf16*)(ws + OFF_C1WB);

  hipFuncSetAttribute((const void*)k_attn2, hipFuncAttributeMaxDynamicSharedMemorySize, SMEM_ATTN);
  hipFuncSetAttribute((const void*)k_mlp_lce2, hipFuncAttributeMaxDynamicSharedMemorySize, 75776);

  // weight converts + c1wb zero-pad + s0 zero, one dispatch
  k_f2b_all<<<1754, 256, 0, stream>>>(qkvw, projw, w1, w2, c1w,
                                      wqkv, wprj, wfc1, wfc2, c1wb, s0);

  // fused attention + LN1 + LCE conv1 (t1), writes x1 into d_out; 2 windows/block
  k_attn2<<<1024, 256, SMEM_ATTN, stream>>>(x, n1g, n1b, wqkv, qkvb, rpb, wprj, projb,
                                            c1wb, c1b, t1, out);
  // FUSED: LCE conv3x3 + pool (blocks 0..511) | 64-token MLP (blocks 512..2559)
  k_mlp_lce2<<<2560, 256, 75776, stream>>>(out, n2g, n2b, wfc1, b1, wfc2, b2,
                                           t1, c2w, c2b, t2, c3w, c3b, s0);
  // FUSED: SE gate + conv1x1 recompute + out += y*gate
  k_final3<<<2048, 192, 0, stream>>>(out, t2, c3w, c3b, s0, sfc1, sfc2);
}